// Round 5
// baseline (399.273 us; speedup 1.0000x reference)
//
#include <hip/hip_runtime.h>
#include <math.h>

// Problem constants
#define BB 4
#define SS 2048
#define DD 1024
#define HH 2048
#define AD 128
#define EE 8
#define MM (BB*SS)   // 8192
#define PS 136       // Psh row stride (u16): 272B, 16B-aligned

typedef unsigned short u16;
typedef short bf16x8 __attribute__((ext_vector_type(8)));
typedef float f32x4 __attribute__((ext_vector_type(4)));
typedef float f32x16 __attribute__((ext_vector_type(16)));

__device__ __forceinline__ float silu_f(float x){ return x / (1.f + __expf(-x)); }

__device__ __forceinline__ u16 f2bf(float f){
    union { float f; unsigned u; } c; c.f = f;
    unsigned r = (c.u + 0x7FFFu + ((c.u >> 16) & 1u)) >> 16;
    return (u16)r;
}

// async global->LDS, 16B per lane. LDS dest must be wave-uniform base + lane*16.
__device__ __forceinline__ void gld16(const u16* g, u16* l){
    __builtin_amdgcn_global_load_lds((const __attribute__((address_space(1))) void*)g,
                                     (__attribute__((address_space(3))) void*)l, 16, 0, 0);
}

#define VMCNT(n) asm volatile("s_waitcnt vmcnt(" #n ")" ::: "memory")

// ---------------------------------------------------------------------------
// Split-K NT GEMM (16x16x32), N fixed = 128. grid = (S, M/128, Z).
// ---------------------------------------------------------------------------
__global__ __launch_bounds__(256,2) void mfma_sk(
    const u16* __restrict__ A, const u16* __restrict__ B, float* __restrict__ P,
    int M, int K, int S, long sA, long sB, long sC, long sSplit)
{
    __shared__ __align__(16) u16 As[128*32];
    __shared__ __align__(16) u16 Bs[128*32];
    const int t = threadIdx.x;
    const int lane = t & 63;
    const int wv = t >> 6;
    const int s = blockIdx.x;
    const int m0 = blockIdx.y * 128;
    const u16* Ab = A + (long)blockIdx.z * sA;
    const u16* Bb = B + (long)blockIdx.z * sB;
    const int srow = t >> 2, scol = (t & 3) * 8;
    const int Ks = K / S, kBeg = s * Ks;
    const u16* ga0 = Ab + (long)(m0 + srow) * K + scol + kBeg;
    const u16* ga1 = ga0 + 64L * K;
    const u16* gb0 = Bb + (long)srow * K + scol + kBeg;
    const u16* gb1 = gb0 + 64L * K;
    u16* la0 = As + t * 8;  u16* la1 = As + 2048 + t * 8;
    u16* lb0 = Bs + t * 8;  u16* lb1 = Bs + 2048 + t * 8;
    const int fr = lane & 15, q = lane >> 4;
    const int wm = (wv & 1) * 64, wn = (wv >> 1) * 64;

    f32x4 acc[4][4] = {};
    for (int k0 = 0; k0 < Ks; k0 += 32) {
        gld16(ga0 + k0, la0);
        gld16(ga1 + k0, la1);
        gld16(gb0 + k0, lb0);
        gld16(gb1 + k0, lb1);
        __syncthreads();
        bf16x8 af[4], bfr[4];
        #pragma unroll
        for (int i = 0; i < 4; ++i) af[i]  = *(const bf16x8*)&As[(wm + i*16 + fr)*32 + q*8];
        #pragma unroll
        for (int i = 0; i < 4; ++i) bfr[i] = *(const bf16x8*)&Bs[(wn + i*16 + fr)*32 + q*8];
        #pragma unroll
        for (int mi = 0; mi < 4; ++mi)
            #pragma unroll
            for (int ni = 0; ni < 4; ++ni)
                acc[mi][ni] = __builtin_amdgcn_mfma_f32_16x16x32_bf16(af[mi], bfr[ni], acc[mi][ni], 0, 0, 0);
        __syncthreads();
    }

    float* Pf = P + (long)s * sSplit + (long)blockIdx.z * sC;
    #pragma unroll
    for (int mi = 0; mi < 4; ++mi)
        #pragma unroll
        for (int ni = 0; ni < 4; ++ni) {
            const int col = wn + ni*16 + fr;
            #pragma unroll
            for (int r = 0; r < 4; ++r) {
                const int row = m0 + wm + mi*16 + q*4 + r;
                Pf[(long)row * 128 + col] = acc[mi][ni][r];
            }
        }
}

// ---------------------------------------------------------------------------
// Fused up/gate, depth-3 pipelined ring, 256(M)x128(N) tile, BK=32, 512 thr.
// 8 waves = 2M x 4N, per-wave 128x32, both U and G accumulators in-wave.
// 4-deep LDS ring (128 KiB), counted vmcnt(8), 1 barrier per K-tile,
// chunk-XOR swizzle via inverse-swizzled global source (rule #21).
// Measured 83.3-84.7 us (R1/R3 best). The 128^2 variant (R4) regressed to
// 99.8: 1.5x staging bytes/FLOP (3 operand panels for half the output rows)
// + shallower prefetch — occupancy was not the binding constraint.
// ---------------------------------------------------------------------------
__global__ __launch_bounds__(512,2) void mfma_upgate(
    const u16* __restrict__ X, const u16* __restrict__ Wu_, const u16* __restrict__ Wg_,
    const float* __restrict__ bu, const float* __restrict__ bg, u16* __restrict__ H)
{
    // ring buffer b (b=0..3) at lds + b*16384 (u16):
    //   A tile 256x32 at +0, Wu tile 128x32 at +8192, Wg tile 128x32 at +12288
    __shared__ __align__(16) u16 lds[65536];   // 128 KiB
    const int t = threadIdx.x, lane = t & 63, wv = t >> 6;
    const int l31 = lane & 31, kh = lane >> 5;
    const int wr = wv >> 2, wc = wv & 3;          // 2M x 4N wave grid
    const int m0 = blockIdx.y * 256, n0 = blockIdx.x * 128;

    // staging: thread t stages 16B; LDS dest linear (t*8 u16);
    // global col pre-swizzled by the involution the reads use (rule #21).
    const int srow = t >> 2;
    const int gcol = (((t & 3) ^ ((t >> 3) & 3)) * 8);
    const u16* gx0 = X   + (long)(m0 + srow) * DD + gcol;
    const u16* gx1 = gx0 + 128L * DD;
    const u16* gu  = Wu_ + (long)(n0 + srow) * DD + gcol;
    const u16* gg  = Wg_ + (long)(n0 + srow) * DD + gcol;
    const int st8 = t * 8;

    // read offsets (u16 units), chunk' = chunk ^ ((row>>1)&3)
    const int sw3 = (l31 >> 1) & 3;
    int offA[4][2], offB[2];
    #pragma unroll
    for (int m = 0; m < 4; ++m)
        #pragma unroll
        for (int ks = 0; ks < 2; ++ks)
            offA[m][ks] = (wr*128 + m*32 + l31)*32 + (((ks*2 + kh) ^ sw3) * 8);
    #pragma unroll
    for (int ks = 0; ks < 2; ++ks)
        offB[ks] = (wc*32 + l31)*32 + (((ks*2 + kh) ^ sw3) * 8);

    f32x16 accU[4] = {};
    f32x16 accG[4] = {};

    auto stage = [&](int tb) {
        u16* Lb = lds + (tb & 3) * 16384;
        const int k0 = tb * 32;
        gld16(gx0 + k0, Lb + st8);
        gld16(gx1 + k0, Lb + 4096 + st8);
        gld16(gu  + k0, Lb + 8192 + st8);
        gld16(gg  + k0, Lb + 12288 + st8);
    };

    auto compute = [&](int tb) {
        const u16* Lb = lds + (tb & 3) * 16384;
        bf16x8 a[4][2], uf[2], gf[2];
        #pragma unroll
        for (int ks = 0; ks < 2; ++ks) {
            uf[ks] = *(const bf16x8*)&Lb[8192  + offB[ks]];
            gf[ks] = *(const bf16x8*)&Lb[12288 + offB[ks]];
        }
        #pragma unroll
        for (int m = 0; m < 4; ++m)
            #pragma unroll
            for (int ks = 0; ks < 2; ++ks)
                a[m][ks] = *(const bf16x8*)&Lb[offA[m][ks]];
        __builtin_amdgcn_s_setprio(1);
        #pragma unroll
        for (int m = 0; m < 4; ++m)
            #pragma unroll
            for (int ks = 0; ks < 2; ++ks) {
                accU[m] = __builtin_amdgcn_mfma_f32_32x32x16_bf16(a[m][ks], uf[ks], accU[m], 0, 0, 0);
                accG[m] = __builtin_amdgcn_mfma_f32_32x32x16_bf16(a[m][ks], gf[ks], accG[m], 0, 0, 0);
            }
        __builtin_amdgcn_s_setprio(0);
    };

    // prologue: 3 tiles in flight (12 loads)
    stage(0); stage(1); stage(2);

    // main loop: wait tile tt (8 newer loads stay in flight), barrier, refill, compute.
    #pragma unroll 1
    for (int tt = 0; tt < 29; ++tt) {
        VMCNT(8);
        __builtin_amdgcn_s_barrier();
        __builtin_amdgcn_sched_barrier(0);
        stage(tt + 3);
        compute(tt);
    }
    VMCNT(8);
    __builtin_amdgcn_s_barrier();
    __builtin_amdgcn_sched_barrier(0);
    compute(29);
    VMCNT(4);
    __builtin_amdgcn_s_barrier();
    __builtin_amdgcn_sched_barrier(0);
    compute(30);
    VMCNT(0);
    __builtin_amdgcn_s_barrier();
    __builtin_amdgcn_sched_barrier(0);
    compute(31);

    // epilogue: per-thread column is fixed
    const int col = n0 + wc*32 + l31;
    const float bub = bu[col], bgb = bg[col];
    u16* Hp = H + (long)(m0 + wr*128) * HH + col;
    #pragma unroll
    for (int m = 0; m < 4; ++m)
        #pragma unroll
        for (int r = 0; r < 16; ++r) {
            const int rowl = m*32 + (r & 3) + 8*(r >> 2) + 4*kh;
            const float u = accU[m][r] + bub;
            const float g = accG[m][r] + bgb;
            Hp[(long)rowl * HH] = f2bf(silu_f(g) * u);
        }
}

// ---------------------------------------------------------------------------
// Final GEMM, depth-3 ring, 128x128, 256 thr (4 waves 2Mx2N, per-wave 64x64).
// out = sumw*(Hh@Wd^T + bd) + 0.1*(Ac@Wcat^T). 72 K-tiles (64 Hh/Wd + 8
// Ac/Wcat). LDS 48 KiB -> 3 blocks/CU; grid (8,64)=512 = 2/CU. VMCNT(4).
// ---------------------------------------------------------------------------
__global__ __launch_bounds__(256,2) void mfma_final(
    const u16* __restrict__ Hh, const u16* __restrict__ Wd_,
    const u16* __restrict__ Ac, const u16* __restrict__ Wcat,
    const float* __restrict__ bd, const float* __restrict__ sumw,
    float* __restrict__ out)
{
    // buf (8192 u16 = 16 KiB): A 128x32 @0, B 128x32 @4096
    __shared__ __align__(16) u16 lds[24576];   // 48 KiB = 3 bufs
    const int t = threadIdx.x, lane = t & 63, wv = t >> 6;
    const int l31 = lane & 31, kh = lane >> 5;
    const int wr = wv & 1, wc = wv >> 1;
    const int m0 = blockIdx.y * 128, n0 = blockIdx.x * 128;

    const int srow = t >> 2;
    const int gcol = (((t & 3) ^ ((t >> 3) & 3)) * 8);
    const u16* gA1 = Hh   + (long)(m0 + srow) * HH  + gcol;
    const u16* gB1 = Wd_  + (long)(n0 + srow) * HH  + gcol;
    const u16* gA2 = Ac   + (long)(m0 + srow) * 256 + gcol;
    const u16* gB2 = Wcat + (long)(n0 + srow) * 256 + gcol;
    const int st8 = t * 8;

    const int sw3 = (l31 >> 1) & 3;
    int offA[2][2], offB[2][2];
    #pragma unroll
    for (int m = 0; m < 2; ++m)
        #pragma unroll
        for (int ks = 0; ks < 2; ++ks) {
            const int ko = ((ks*2 + kh) ^ sw3) * 8;
            offA[m][ks] =        (wr*64 + m*32 + l31)*32 + ko;
            offB[m][ks] = 4096 + (wc*64 + m*32 + l31)*32 + ko;
        }

    f32x16 acc[2][2]  = {};
    f32x16 acc2[2][2] = {};

    auto stage = [&](int tk) {
        u16* Lb = lds + (tk % 3) * 8192;
        if (tk < 64) {
            const int k0 = tk * 32;
            gld16(gA1 + k0,           Lb + st8);
            gld16(gA1 + 64L*HH + k0,  Lb + 2048 + st8);
            gld16(gB1 + k0,           Lb + 4096 + st8);
            gld16(gB1 + 64L*HH + k0,  Lb + 6144 + st8);
        } else {
            const int k0 = (tk - 64) * 32;
            gld16(gA2 + k0,           Lb + st8);
            gld16(gA2 + 64L*256 + k0, Lb + 2048 + st8);
            gld16(gB2 + k0,           Lb + 4096 + st8);
            gld16(gB2 + 64L*256 + k0, Lb + 6144 + st8);
        }
    };

    auto compute = [&](int tk, f32x16 (&A)[2][2]) {
        const u16* Lb = lds + (tk % 3) * 8192;
        bf16x8 a[2][2], b[2][2];
        #pragma unroll
        for (int m = 0; m < 2; ++m)
            #pragma unroll
            for (int ks = 0; ks < 2; ++ks) {
                a[m][ks] = *(const bf16x8*)&Lb[offA[m][ks]];
                b[m][ks] = *(const bf16x8*)&Lb[offB[m][ks]];
            }
        __builtin_amdgcn_s_setprio(1);
        #pragma unroll
        for (int m = 0; m < 2; ++m)
            #pragma unroll
            for (int n = 0; n < 2; ++n)
                #pragma unroll
                for (int ks = 0; ks < 2; ++ks)
                    A[m][n] = __builtin_amdgcn_mfma_f32_32x32x16_bf16(a[m][ks], b[n][ks], A[m][n], 0, 0, 0);
        __builtin_amdgcn_s_setprio(0);
    };

    stage(0); stage(1);
    #pragma unroll 1
    for (int tt = 0; tt < 70; ++tt) {
        VMCNT(4);
        __builtin_amdgcn_s_barrier();
        __builtin_amdgcn_sched_barrier(0);
        stage(tt + 2);
        if (tt < 64) compute(tt, acc); else compute(tt, acc2);
    }
    VMCNT(4);
    __builtin_amdgcn_s_barrier();
    __builtin_amdgcn_sched_barrier(0);
    compute(70, acc2);
    VMCNT(0);
    __builtin_amdgcn_s_barrier();
    __builtin_amdgcn_sched_barrier(0);
    compute(71, acc2);

    // epilogue
    #pragma unroll
    for (int n = 0; n < 2; ++n) {
        const int col = n0 + wc*64 + n*32 + l31;
        const float bdc = bd[col];
        #pragma unroll
        for (int m = 0; m < 2; ++m)
            #pragma unroll
            for (int r = 0; r < 16; ++r) {
                const int row = m0 + wr*64 + m*32 + (r & 3) + 8*(r >> 2) + 4*kh;
                out[(long)row * DD + col] =
                    sumw[row] * (acc[m][n][r] + bdc) + 0.1f * acc2[m][n][r];
            }
    }
}

// ---------------------------------------------------------------------------
// Flash with deterministic T-partials. grid = (8 t-groups, 16 s-tiles, 4 b).
// ---------------------------------------------------------------------------
__global__ __launch_bounds__(256,2) void flash_pv(
    const u16* __restrict__ ai, const u16* __restrict__ ao,
    const u16* __restrict__ aiT, float* __restrict__ adaptP)
{
    __shared__ __align__(16) u16 As[128*32];
    __shared__ __align__(16) u16 Bs[128*32];
    __shared__ __align__(16) u16 Psh[128*PS];
    const int t = threadIdx.x, lane = t & 63, wv = t >> 6;
    const int fr = lane & 15, q = lane >> 4;
    const int wm = (wv & 1) * 64, wn = (wv >> 1) * 64;
    const int tg = blockIdx.x, s0 = blockIdx.y * 128, b = blockIdx.z;
    const u16* aib  = ai  + (long)b * SS * AD;
    const u16* aob  = ao  + (long)b * SS * AD;
    const u16* aiTb = aiT + (long)b * AD * SS;
    const int srow = t >> 2, scol = (t & 3) * 8;
    u16* la0 = As + t * 8;  u16* la1 = As + 2048 + t * 8;
    u16* lb0 = Bs + t * 8;  u16* lb1 = Bs + 2048 + t * 8;
    const u16* ga0 = aib + (long)(s0 + srow) * AD + scol;
    const u16* ga1 = ga0 + 64L * AD;

    f32x4 vacc[4][4] = {};
    for (int ti = 0; ti < 2; ++ti) {
        const int t0 = tg * 256 + ti * 128;
        const u16* gb0 = aob + (long)(t0 + srow) * AD + scol;
        const u16* gb1 = gb0 + 64L * AD;
        f32x4 acc[4][4] = {};
        for (int k0 = 0; k0 < AD; k0 += 32) {
            gld16(ga0 + k0, la0);
            gld16(ga1 + k0, la1);
            gld16(gb0 + k0, lb0);
            gld16(gb1 + k0, lb1);
            __syncthreads();
            bf16x8 af[4], bfr[4];
            #pragma unroll
            for (int i = 0; i < 4; ++i) af[i]  = *(const bf16x8*)&As[(wm + i*16 + fr)*32 + q*8];
            #pragma unroll
            for (int i = 0; i < 4; ++i) bfr[i] = *(const bf16x8*)&Bs[(wn + i*16 + fr)*32 + q*8];
            #pragma unroll
            for (int mi = 0; mi < 4; ++mi)
                #pragma unroll
                for (int ni = 0; ni < 4; ++ni)
                    acc[mi][ni] = __builtin_amdgcn_mfma_f32_16x16x32_bf16(af[mi], bfr[ni], acc[mi][ni], 0, 0, 0);
            __syncthreads();
        }
        // P -> Psh (bf16)
        #pragma unroll
        for (int mi = 0; mi < 4; ++mi)
            #pragma unroll
            for (int ni = 0; ni < 4; ++ni)
                #pragma unroll
                for (int r = 0; r < 4; ++r) {
                    float v = acc[mi][ni][r];
                    v = fminf(fmaxf(v, -5.f), 5.f);
                    Psh[(wm + mi*16 + q*4 + r)*PS + wn + ni*16 + fr] = f2bf(silu_f(v));
                }
        __syncthreads();
        // PV: vacc += Psh @ aiT-tile (B frags direct from global, L2-hot)
        #pragma unroll
        for (int kk = 0; kk < 4; ++kk) {
            bf16x8 pf[4], bi[4];
            #pragma unroll
            for (int mi = 0; mi < 4; ++mi)
                pf[mi] = *(const bf16x8*)&Psh[(wm + mi*16 + fr)*PS + kk*32 + q*8];
            #pragma unroll
            for (int ni = 0; ni < 4; ++ni)
                bi[ni] = *(const bf16x8*)&aiTb[(long)(wn + ni*16 + fr)*SS + t0 + kk*32 + q*8];
            #pragma unroll
            for (int mi = 0; mi < 4; ++mi)
                #pragma unroll
                for (int ni = 0; ni < 4; ++ni)
                    vacc[mi][ni] = __builtin_amdgcn_mfma_f32_16x16x32_bf16(pf[mi], bi[ni], vacc[mi][ni], 0, 0, 0);
        }
    }
    float* Pf = adaptP + (long)tg * MM * AD + (long)(b * SS + s0) * AD;
    #pragma unroll
    for (int mi = 0; mi < 4; ++mi)
        #pragma unroll
        for (int ni = 0; ni < 4; ++ni) {
            const int col = wn + ni*16 + fr;
            #pragma unroll
            for (int r = 0; r < 4; ++r) {
                const int row = wm + mi*16 + q*4 + r;
                Pf[(long)row * AD + col] = vacc[mi][ni][r];
            }
        }
}

// Sum 8 T-partials * sumw -> acat[:,128:256] bf16.
__global__ __launch_bounds__(256) void scale_adapt(
    const float* __restrict__ P, const float* __restrict__ sumw, u16* __restrict__ acat)
{
    const int i = blockIdx.x * 256 + threadIdx.x;   // MM*AD/4
    float4 v = ((const float4*)P)[i];
    #pragma unroll
    for (int tg = 1; tg < 8; ++tg) {
        const float4 w = ((const float4*)P)[i + (long)tg * (MM*AD/4)];
        v.x += w.x; v.y += w.y; v.z += w.z; v.w += w.w;
    }
    const long grow = i >> 5;
    const float sw = sumw[grow];
    ushort4 o;
    o.x = f2bf(sw*v.x); o.y = f2bf(sw*v.y); o.z = f2bf(sw*v.z); o.w = f2bf(sw*v.w);
    ((ushort4*)acat)[grow*64 + 32 + (i & 31)] = o;
}

// ---------------------------------------------------------------------------
// Fused expert branch, 32-row blocks (grid MM/32 = 256). 4 waves:
// (wv&1) = row half, (wv>>1) = expert half {0-3 | 4-7}; LDS combine.
// ---------------------------------------------------------------------------
__global__ __launch_bounds__(256) void expert_fused(
    const u16* __restrict__ pre, const u16* __restrict__ aexp,
    const float* __restrict__ ew, const float* __restrict__ eg,
    const float* __restrict__ eb, u16* __restrict__ acat,
    float* __restrict__ sumw)
{
    __shared__ float ewsh[32*8];
    __shared__ float egsh[8*128], ebsh[8*128];
    __shared__ float part[32*132];   // padded stride vs bank conflicts
    const int t = threadIdx.x, lane = t & 63, wv = t >> 6;
    const int fr = lane & 15, q = lane >> 4;
    const int wm = (wv & 1) * 16;
    const int e0 = (wv >> 1) * 4;
    const int m0 = blockIdx.x * 32;
    if (t < 64) {
        const int row = t >> 1, j = (t & 1)*4;
        *(float4*)&ewsh[row*8+j] = *(const float4*)&ew[(long)(m0+row)*EE + j];
    }
    {   const int e = t >> 5, c = (t & 31)*4;
        *(float4*)&egsh[e*128+c] = *(const float4*)&eg[e*128+c];
        *(float4*)&ebsh[e*128+c] = *(const float4*)&eb[e*128+c]; }
    __syncthreads();

    f32x4 hwacc[8] = {};
    for (int ee = 0; ee < 4; ++ee) {
        const int e = e0 + ee;
        f32x4 acc[8] = {};
        const u16* Ae = aexp + (long)e * AD * AD;
        #pragma unroll
        for (int ks = 0; ks < 4; ++ks) {
            bf16x8 af, bfr[8];
            af = *(const bf16x8*)&pre[(long)(m0 + wm + fr)*AD + ks*32 + q*8];
            #pragma unroll
            for (int ni = 0; ni < 8; ++ni)
                bfr[ni] = *(const bf16x8*)&Ae[(long)(ni*16 + fr)*AD + ks*32 + q*8];
            #pragma unroll
            for (int ni = 0; ni < 8; ++ni)
                acc[ni] = __builtin_amdgcn_mfma_f32_16x16x32_bf16(af, bfr[ni], acc[ni], 0, 0, 0);
        }
        #pragma unroll
        for (int r = 0; r < 4; ++r) {
            float s = 0.f, s2 = 0.f;
            #pragma unroll
            for (int ni = 0; ni < 8; ++ni) { const float v = acc[ni][r]; s += v; s2 += v*v; }
            #pragma unroll
            for (int msk = 1; msk < 16; msk <<= 1) {
                s  += __shfl_xor(s,  msk, 64);
                s2 += __shfl_xor(s2, msk, 64);
            }
            const float mean = s * (1.f/128.f);
            const float var  = s2 * (1.f/128.f) - mean*mean;
            const float rs   = rsqrtf(var + 1e-5f);
            const int rowl = wm + q*4 + r;
            float w = ewsh[rowl*8 + e]; w = w > 0.f ? w : 0.f;
            #pragma unroll
            for (int ni = 0; ni < 8; ++ni) {
                const int col = ni*16 + fr;
                hwacc[ni][r] += w * ((acc[ni][r] - mean) * rs * egsh[e*128+col] + ebsh[e*128+col]);
            }
        }
    }
    if (wv >= 2) {
        #pragma unroll
        for (int r = 0; r < 4; ++r) {
            const int rowl = wm + q*4 + r;
            #pragma unroll
            for (int ni = 0; ni < 8; ++ni)
                part[rowl*132 + ni*16 + fr] = hwacc[ni][r];
        }
    }
    __syncthreads();
    if (wv < 2) {
        #pragma unroll
        for (int r = 0; r < 4; ++r) {
            const int rowl = wm + q*4 + r;
            #pragma unroll
            for (int ni = 0; ni < 8; ++ni) {
                const float v = hwacc[ni][r] + part[rowl*132 + ni*16 + fr];
                acat[(long)(m0+rowl)*256 + ni*16 + fr] = f2bf(v);
            }
            if (fr == 0) {
                float sw = 0.f;
                #pragma unroll
                for (int j = 0; j < 8; ++j) sw += ewsh[rowl*8 + j];
                sumw[m0 + rowl] = sw;
            }
        }
    }
}

// ---------------------------------------------------------------------------
// Split-K reduce + bias + (optional raw bf16 out) + LayerNorm(128) -> bf16.
// ---------------------------------------------------------------------------
template<int S>
__global__ __launch_bounds__(128) void ln_reduce(
    const float* __restrict__ P, long sSplit, const float* __restrict__ bias,
    u16* __restrict__ raw, u16* __restrict__ ln_out,
    const float* __restrict__ g, const float* __restrict__ b)
{
    const int r = blockIdx.x, tid = threadIdx.x;
    float v = bias[tid];
    #pragma unroll
    for (int s = 0; s < S; ++s) v += P[(long)s * sSplit + (long)r * AD + tid];
    if (raw) raw[(long)r * AD + tid] = f2bf(v);
    __shared__ float red[AD], red2[AD];
    red[tid] = v; red2[tid] = v*v;
    __syncthreads();
    for (int s = 64; s > 0; s >>= 1) {
        if (tid < s) { red[tid] += red[tid+s]; red2[tid] += red2[tid+s]; }
        __syncthreads();
    }
    const float mean = red[0] * (1.f/AD);
    const float var  = red2[0] * (1.f/AD) - mean*mean;
    const float rs   = rsqrtf(var + 1e-5f);
    ln_out[(long)r * AD + tid] = f2bf((v - mean) * rs * g[tid] + b[tid]);
}

// Reduce wc partials (S=16, z=2) -> Wcat [1024, 256] bf16.
__global__ __launch_bounds__(256) void reduce_cat(
    const float* __restrict__ P, u16* __restrict__ Wcat)
{
    const int i = blockIdx.x * 256 + threadIdx.x;   // 65536 total
    const int a4 = i & 31, z = (i >> 5) & 1, d = i >> 6;
    const float* src = P + (long)z * (16L*DD*AD) + (long)d * AD + a4*4;
    float4 v = *(const float4*)src;
    #pragma unroll
    for (int s = 1; s < 16; ++s) {
        const float4 w = *(const float4*)(src + (long)s * DD * AD);
        v.x += w.x; v.y += w.y; v.z += w.z; v.w += w.w;
    }
    ushort4 o; o.x=f2bf(v.x); o.y=f2bf(v.y); o.z=f2bf(v.z); o.w=f2bf(v.w);
    ((ushort4*)Wcat)[(long)d*64 + z*32 + a4] = o;
}

// Combined bf16 transpose [2048,128]->[128,2048]: z<2: Wp/Wap; z>=2: ai batch z-2.
__global__ __launch_bounds__(256) void transpose6(
    const u16* __restrict__ wRaw, u16* __restrict__ wT,
    const u16* __restrict__ ai, u16* __restrict__ aiT)
{
    __shared__ u16 tile[32][33];
    const int z = blockIdx.z;
    const u16* in; u16* out;
    if (z < 2) { in = wRaw + (long)z * HH * AD; out = wT + (long)z * AD * HH; }
    else       { in = ai + (long)(z-2) * SS * AD; out = aiT + (long)(z-2) * AD * SS; }
    const int x0 = blockIdx.x * 32, y0 = blockIdx.y * 32;
    const int tx = threadIdx.x & 31, ty = threadIdx.x >> 5;
    #pragma unroll
    for (int j = 0; j < 4; ++j)
        tile[ty + j*8][tx] = in[(long)(y0 + ty + j*8) * AD + x0 + tx];
    __syncthreads();
    #pragma unroll
    for (int j = 0; j < 4; ++j)
        out[(long)(x0 + ty + j*8) * SS + y0 + tx] = tile[tx][ty + j*8];
}

// Packed f32->bf16 convert: 5 segments, 4 elems/thread. cum[] in float4 units.
struct Cvt5 { const float* in[5]; u16* out[5]; long cum[6]; };
__global__ __launch_bounds__(256) void cvt_pack(Cvt5 a)
{
    const long i = (long)blockIdx.x * 256 + threadIdx.x;
    if (i >= a.cum[5]) return;
    int s = 0;
    while (i >= a.cum[s+1]) ++s;
    const long j = i - a.cum[s];
    const float4 v = ((const float4*)a.in[s])[j];
    ushort4 o;
    o.x = f2bf(v.x); o.y = f2bf(v.y); o.z = f2bf(v.z); o.w = f2bf(v.w);
    ((ushort4*)a.out[s])[j] = o;
}

extern "C" void kernel_launch(void* const* d_in, const int* in_sizes, int n_in,
                              void* d_out, int out_size, void* d_ws, size_t ws_size,
                              hipStream_t stream) {
    const float* x    = (const float*)d_in[0];
    const float* ew   = (const float*)d_in[1];
    const float* Wu   = (const float*)d_in[2];
    const float* bu   = (const float*)d_in[3];
    const float* Wg   = (const float*)d_in[4];
    const float* bg   = (const float*)d_in[5];
    const float* Wd   = (const float*)d_in[6];
    const float* bd   = (const float*)d_in[7];
    const float* Wpre = (const float*)d_in[8];
    const float* bpre = (const float*)d_in[9];
    const float* Wpost= (const float*)d_in[10];
    const float* bpost= (const float*)d_in[11];
    const float* ln_g = (const float*)d_in[12];
    const float* ln_b = (const float*)d_in[13];
    const float* Wap  = (const float*)d_in[14];
    const float* Aex  = (const float*)d_in[15];
    const float* eg   = (const float*)d_in[16];
    const float* eb   = (const float*)d_in[17];
    const float* Wp   = (const float*)d_in[18];
    const float* Wo   = (const float*)d_in[19];
    float* out = (float*)d_out;

    // ---- workspace layout ----
    char* p = (char*)d_ws;
    auto take = [&](long bytes) -> char* {
        char* r = p; p += (bytes + 255) & ~255L; return r;
    };
    u16* x_slot  = (u16*)take(16777216);          // x_bf phase1; sub-slots phase2
    u16* wslot   = (u16*)take((long)2*DD*HH*2);   // 8MB: [Wu|Wg] then [Wo|Wd]
    u16* wpre    = (u16*)take((long)AD*DD*2);
    u16* aex     = (u16*)take((long)EE*AD*AD*2);
    u16* pre_bf  = (u16*)take((long)MM*AD*2);
    u16* ai_bf   = (u16*)take((long)MM*AD*2);
    char* shareA = take(33554432);                // preP(16MB)/wcP(16MB@+16)/wpostP(32MB)/adaptP(32MB)
    u16* acat    = (u16*)take((long)MM*256*2);    // [hw | sumw*adapt]
    float* sumw  = (float*)take((long)MM*4);
    u16* hidden  = (u16*)take((long)MM*HH*2);

    // x_slot sub-layout (phase 2):
    u16* x_bf    = x_slot;
    u16* aiT     = x_slot;                         // 4*128*2048 = 1,048,576 u16
    u16* wRaw    = aiT  + 1048576;                 // [Wp|Wap]: 524,288
    u16* wT      = wRaw + 524288;                  // [WpT|WapT]: 524,288
    u16* wpost_w = wT   + 524288;                  // 262,144
    u16* wcat    = wpost_w + 262144;               // 262,144
    u16* ao_bf   = wcat + 262144;                  // 1,048,576
    float* preP   = (float*)shareA;
    float* wcP    = (float*)(shareA + 16777216);   // 16MB (steps 8-9; preP dead)
    float* wpostP = (float*)shareA;
    float* adaptP = (float*)shareA;                // 8 x MM*AD f32 = 32MB

    // 1. converts phase 1: x, Wu, Wg, Wpre, Aex
    {
        Cvt5 a;
        a.in[0]=x;    a.out[0]=x_bf;              long n0=(long)MM*DD/4;
        a.in[1]=Wu;   a.out[1]=wslot;             long n1=(long)HH*DD/4;
        a.in[2]=Wg;   a.out[2]=wslot+(long)DD*HH; long n2=(long)HH*DD/4;
        a.in[3]=Wpre; a.out[3]=wpre;              long n3=(long)AD*DD/4;
        a.in[4]=Aex;  a.out[4]=aex;               long n4=(long)EE*AD*AD/4;
        a.cum[0]=0; a.cum[1]=n0; a.cum[2]=n0+n1; a.cum[3]=n0+n1+n2;
        a.cum[4]=n0+n1+n2+n3; a.cum[5]=n0+n1+n2+n3+n4;
        cvt_pack<<<dim3((a.cum[5]+255)/256), 256, 0, stream>>>(a);
    }
    // 2. pre partials: x @ Wpre^T, split-K S=4
    mfma_sk<<<dim3(4, MM/128, 1), 256, 0, stream>>>(
        x_bf, wpre, preP, MM, DD, 4, 0, 0, 0, (long)MM*AD);
    // 3. reduce + bpre -> pre_bf (raw) and ai_bf (LN)
    ln_reduce<4><<<dim3(MM), 128, 0, stream>>>(preP, (long)MM*AD, bpre, pre_bf, ai_bf, ln_g, ln_b);
    // 4. fused expert branch -> acat[:,0:128], sumw  [32-row blocks, grid 256]
    expert_fused<<<dim3(MM/32), 256, 0, stream>>>(pre_bf, aex, ew, eg, eb, acat, sumw);
    // 5. hidden = bf16(silu(x@Wg^T+bg)*(x@Wu^T+bu))  [256x128 depth-3 ring]
    mfma_upgate<<<dim3(HH/128, MM/256), 512, 0, stream>>>(
        x_bf, wslot, wslot+(long)DD*HH, bu, bg, hidden);
    // 6. converts phase 2: Wo, Wd, Wpost, Wp, Wap  (x_bf/Wu/Wg dead)
    {
        Cvt5 a;
        a.in[0]=Wo;    a.out[0]=wslot;             long n0=(long)DD*HH/4;
        a.in[1]=Wd;    a.out[1]=wslot+(long)DD*HH; long n1=(long)DD*HH/4;
        a.in[2]=Wpost; a.out[2]=wpost_w;           long n2=(long)AD*HH/4;
        a.in[3]=Wp;    a.out[3]=wRaw;              long n3=(long)HH*AD/4;
        a.in[4]=Wap;   a.out[4]=wRaw+(long)HH*AD;  long n4=(long)HH*AD/4;
        a.cum[0]=0; a.cum[1]=n0; a.cum[2]=n0+n1; a.cum[3]=n0+n1+n2;
        a.cum[4]=n0+n1+n2+n3; a.cum[5]=n0+n1+n2+n3+n4;
        cvt_pack<<<dim3((a.cum[5]+255)/256), 256, 0, stream>>>(a);
    }
    // 7. transposes: [WpT|WapT] (z=0,1) and aiT per batch (z=2..5)
    transpose6<<<dim3(4,64,6), 256, 0, stream>>>(wRaw, wT, ai_bf, aiT);
    // 8. Wc=Wo@Wp, Wdap=Wd@Wap: split-K S=16 (grid 256)
    mfma_sk<<<dim3(16, DD/128, 2), 256, 0, stream>>>(
        wslot, wT, wcP, DD, HH, 16, (long)DD*HH, (long)AD*HH, 16L*DD*AD, (long)DD*AD);
    // 9. Wcat[d, 0:128]=Wc, [128:256]=Wdap
    reduce_cat<<<dim3(256), 256, 0, stream>>>(wcP, wcat);
    // 10. hidden @ Wpost^T partials, split-K S=8
    mfma_sk<<<dim3(8, MM/128, 1), 256, 0, stream>>>(
        hidden, wpost_w, wpostP, MM, HH, 8, 0, 0, 0, (long)MM*AD);
    // 11. ao_bf = LN(. + bpost)
    ln_reduce<8><<<dim3(MM), 128, 0, stream>>>(wpostP, (long)MM*AD, bpost, nullptr, ao_bf, ln_g, ln_b);
    // 12. flash: adaptP[tg] = partial_t( silu(clip(ai@ao^T)) @ ai )
    flash_pv<<<dim3(8, SS/128, BB), 256, 0, stream>>>(ai_bf, ao_bf, aiT, adaptP);
    // 13. acat[:,128:256] = bf16(sumw * sum_tg adaptP)
    scale_adapt<<<dim3((long)MM*AD/4/256), 256, 0, stream>>>(adaptP, sumw, acat);
    // 14. out = sumw*(hidden@Wd^T + bd) + 0.1*(acat@Wcat^T)  [128^2 ring, grid 512]
    mfma_final<<<dim3(DD/128, MM/128), 256, 0, stream>>>(
        hidden, wslot+(long)DD*HH, acat, wcat, bd, sumw, out);
}

// Round 8
// 391.574 us; speedup vs baseline: 1.0197x; 1.0197x over previous
//
#include <hip/hip_runtime.h>
#include <math.h>

// Problem constants
#define BB 4
#define SS 2048
#define DD 1024
#define HH 2048
#define AD 128
#define EE 8
#define MM (BB*SS)   // 8192
#define PS 136       // Psh row stride (u16): 272B, 16B-aligned

typedef unsigned short u16;
typedef short bf16x8 __attribute__((ext_vector_type(8)));
typedef float f32x4 __attribute__((ext_vector_type(4)));
typedef float f32x16 __attribute__((ext_vector_type(16)));

__device__ __forceinline__ float silu_f(float x){ return x / (1.f + __expf(-x)); }

__device__ __forceinline__ u16 f2bf(float f){
    union { float f; unsigned u; } c; c.f = f;
    unsigned r = (c.u + 0x7FFFu + ((c.u >> 16) & 1u)) >> 16;
    return (u16)r;
}

// async global->LDS, 16B per lane. LDS dest must be wave-uniform base + lane*16.
__device__ __forceinline__ void gld16(const u16* g, u16* l){
    __builtin_amdgcn_global_load_lds((const __attribute__((address_space(1))) void*)g,
                                     (__attribute__((address_space(3))) void*)l, 16, 0, 0);
}

#define VMCNT(n) asm volatile("s_waitcnt vmcnt(" #n ")" ::: "memory")

// ---------------------------------------------------------------------------
// Split-K NT GEMM (16x16x32), N fixed = 128. grid = (S, M/128, Z).
// Depth-4 ring (64 KiB -> 2 blocks/CU), stage-ahead-3, VMCNT(8),
// 1 barrier/K-tile, chunk-XOR swizzle via inverse-swizzled global source.
// RING INVARIANT: depth(4) > stage_ahead(3) — R7's depth-3/ahead-3 raced
// (stage(tt+3) hit the buffer compute(tt) was reading; absmax 0.59).
// Requires Ks/32 >= 4 (call sites: NT = 8, 4, 16).
// ---------------------------------------------------------------------------
__global__ __launch_bounds__(256,2) void mfma_sk(
    const u16* __restrict__ A, const u16* __restrict__ B, float* __restrict__ P,
    int M, int K, int S, long sA, long sB, long sC, long sSplit)
{
    __shared__ __align__(16) u16 lds[32768];   // 4 bufs x 8192 u16 (As 4096 | Bs 4096)
    const int t = threadIdx.x;
    const int lane = t & 63;
    const int wv = t >> 6;
    const int s = blockIdx.x;
    const int m0 = blockIdx.y * 128;
    const u16* Ab = A + (long)blockIdx.z * sA;
    const u16* Bb = B + (long)blockIdx.z * sB;
    const int srow = t >> 2;
    const int gcol = (((t & 3) ^ ((t >> 3) & 3)) * 8);   // pre-swizzled source col
    const int Ks = K / S, kBeg = s * Ks;
    const int NT = Ks >> 5;
    const u16* ga0 = Ab + (long)(m0 + srow) * K + gcol + kBeg;
    const u16* ga1 = ga0 + 64L * K;
    const u16* gb0 = Bb + (long)srow * K + gcol + kBeg;
    const u16* gb1 = gb0 + 64L * K;
    const int fr = lane & 15, q = lane >> 4;
    const int wm = (wv & 1) * 64, wn = (wv >> 1) * 64;
    const int st8 = t * 8;

    // read-side swizzle: chunk' = chunk ^ ((row>>1)&3); row bases mult of 16
    const int sw3 = (fr >> 1) & 3;
    const int koff = (q ^ sw3) * 8;

    f32x4 acc[4][4] = {};

    auto stage = [&](int tk) {
        u16* Lb = lds + (tk & 3) * 8192;
        const int k0 = tk * 32;
        gld16(ga0 + k0, Lb + st8);
        gld16(ga1 + k0, Lb + 2048 + st8);
        gld16(gb0 + k0, Lb + 4096 + st8);
        gld16(gb1 + k0, Lb + 6144 + st8);
    };
    auto compute = [&](int tk) {
        const u16* Lb = lds + (tk & 3) * 8192;
        bf16x8 af[4], bfr[4];
        #pragma unroll
        for (int i = 0; i < 4; ++i) af[i]  = *(const bf16x8*)&Lb[(wm + i*16 + fr)*32 + koff];
        #pragma unroll
        for (int i = 0; i < 4; ++i) bfr[i] = *(const bf16x8*)&Lb[4096 + (wn + i*16 + fr)*32 + koff];
        __builtin_amdgcn_s_setprio(1);
        #pragma unroll
        for (int mi = 0; mi < 4; ++mi)
            #pragma unroll
            for (int ni = 0; ni < 4; ++ni)
                acc[mi][ni] = __builtin_amdgcn_mfma_f32_16x16x32_bf16(af[mi], bfr[ni], acc[mi][ni], 0, 0, 0);
        __builtin_amdgcn_s_setprio(0);
    };

    stage(0); stage(1); stage(2);
    #pragma unroll 1
    for (int tt = 0; tt < NT - 3; ++tt) {
        VMCNT(8);
        __builtin_amdgcn_s_barrier();
        __builtin_amdgcn_sched_barrier(0);
        stage(tt + 3);
        compute(tt);
    }
    VMCNT(8);
    __builtin_amdgcn_s_barrier();
    __builtin_amdgcn_sched_barrier(0);
    compute(NT - 3);
    VMCNT(4);
    __builtin_amdgcn_s_barrier();
    __builtin_amdgcn_sched_barrier(0);
    compute(NT - 2);
    VMCNT(0);
    __builtin_amdgcn_s_barrier();
    __builtin_amdgcn_sched_barrier(0);
    compute(NT - 1);

    float* Pf = P + (long)s * sSplit + (long)blockIdx.z * sC;
    #pragma unroll
    for (int mi = 0; mi < 4; ++mi)
        #pragma unroll
        for (int ni = 0; ni < 4; ++ni) {
            const int col = wn + ni*16 + fr;
            #pragma unroll
            for (int r = 0; r < 4; ++r) {
                const int row = m0 + wm + mi*16 + q*4 + r;
                Pf[(long)row * 128 + col] = acc[mi][ni][r];
            }
        }
}

// ---------------------------------------------------------------------------
// Fused up/gate, depth-3 pipelined ring, 256(M)x128(N) tile, BK=32, 512 thr.
// 8 waves = 2M x 4N, per-wave 128x32, both U and G accumulators in-wave.
// 4-deep LDS ring (128 KiB), counted vmcnt(8), 1 barrier per K-tile.
// Measured 83.3-84.7 us (R1/R3/R5). Register-bound at 1 block/CU
// (228 unified regs x 8 waves = 1824/2048) — occupancy is not the lever (R4).
// ---------------------------------------------------------------------------
__global__ __launch_bounds__(512,2) void mfma_upgate(
    const u16* __restrict__ X, const u16* __restrict__ Wu_, const u16* __restrict__ Wg_,
    const float* __restrict__ bu, const float* __restrict__ bg, u16* __restrict__ H)
{
    // ring buffer b (b=0..3) at lds + b*16384 (u16):
    //   A tile 256x32 at +0, Wu tile 128x32 at +8192, Wg tile 128x32 at +12288
    __shared__ __align__(16) u16 lds[65536];   // 128 KiB
    const int t = threadIdx.x, lane = t & 63, wv = t >> 6;
    const int l31 = lane & 31, kh = lane >> 5;
    const int wr = wv >> 2, wc = wv & 3;          // 2M x 4N wave grid
    const int m0 = blockIdx.y * 256, n0 = blockIdx.x * 128;

    const int srow = t >> 2;
    const int gcol = (((t & 3) ^ ((t >> 3) & 3)) * 8);
    const u16* gx0 = X   + (long)(m0 + srow) * DD + gcol;
    const u16* gx1 = gx0 + 128L * DD;
    const u16* gu  = Wu_ + (long)(n0 + srow) * DD + gcol;
    const u16* gg  = Wg_ + (long)(n0 + srow) * DD + gcol;
    const int st8 = t * 8;

    const int sw3 = (l31 >> 1) & 3;
    int offA[4][2], offB[2];
    #pragma unroll
    for (int m = 0; m < 4; ++m)
        #pragma unroll
        for (int ks = 0; ks < 2; ++ks)
            offA[m][ks] = (wr*128 + m*32 + l31)*32 + (((ks*2 + kh) ^ sw3) * 8);
    #pragma unroll
    for (int ks = 0; ks < 2; ++ks)
        offB[ks] = (wc*32 + l31)*32 + (((ks*2 + kh) ^ sw3) * 8);

    f32x16 accU[4] = {};
    f32x16 accG[4] = {};

    auto stage = [&](int tb) {
        u16* Lb = lds + (tb & 3) * 16384;
        const int k0 = tb * 32;
        gld16(gx0 + k0, Lb + st8);
        gld16(gx1 + k0, Lb + 4096 + st8);
        gld16(gu  + k0, Lb + 8192 + st8);
        gld16(gg  + k0, Lb + 12288 + st8);
    };

    auto compute = [&](int tb) {
        const u16* Lb = lds + (tb & 3) * 16384;
        bf16x8 a[4][2], uf[2], gf[2];
        #pragma unroll
        for (int ks = 0; ks < 2; ++ks) {
            uf[ks] = *(const bf16x8*)&Lb[8192  + offB[ks]];
            gf[ks] = *(const bf16x8*)&Lb[12288 + offB[ks]];
        }
        #pragma unroll
        for (int m = 0; m < 4; ++m)
            #pragma unroll
            for (int ks = 0; ks < 2; ++ks)
                a[m][ks] = *(const bf16x8*)&Lb[offA[m][ks]];
        __builtin_amdgcn_s_setprio(1);
        #pragma unroll
        for (int m = 0; m < 4; ++m)
            #pragma unroll
            for (int ks = 0; ks < 2; ++ks) {
                accU[m] = __builtin_amdgcn_mfma_f32_32x32x16_bf16(a[m][ks], uf[ks], accU[m], 0, 0, 0);
                accG[m] = __builtin_amdgcn_mfma_f32_32x32x16_bf16(a[m][ks], gf[ks], accG[m], 0, 0, 0);
            }
        __builtin_amdgcn_s_setprio(0);
    };

    stage(0); stage(1); stage(2);
    #pragma unroll 1
    for (int tt = 0; tt < 29; ++tt) {
        VMCNT(8);
        __builtin_amdgcn_s_barrier();
        __builtin_amdgcn_sched_barrier(0);
        stage(tt + 3);
        compute(tt);
    }
    VMCNT(8);
    __builtin_amdgcn_s_barrier();
    __builtin_amdgcn_sched_barrier(0);
    compute(29);
    VMCNT(4);
    __builtin_amdgcn_s_barrier();
    __builtin_amdgcn_sched_barrier(0);
    compute(30);
    VMCNT(0);
    __builtin_amdgcn_s_barrier();
    __builtin_amdgcn_sched_barrier(0);
    compute(31);

    const int col = n0 + wc*32 + l31;
    const float bub = bu[col], bgb = bg[col];
    u16* Hp = H + (long)(m0 + wr*128) * HH + col;
    #pragma unroll
    for (int m = 0; m < 4; ++m)
        #pragma unroll
        for (int r = 0; r < 16; ++r) {
            const int rowl = m*32 + (r & 3) + 8*(r >> 2) + 4*kh;
            const float u = accU[m][r] + bub;
            const float g = accG[m][r] + bgb;
            Hp[(long)rowl * HH] = f2bf(silu_f(g) * u);
        }
}

// ---------------------------------------------------------------------------
// Final GEMM, depth-3 ring (stage-ahead-2), 128x128, 256 thr (4 waves 2Mx2N,
// per-wave 64x64). out = sumw*(Hh@Wd^T + bd) + 0.1*(Ac@Wcat^T). 72 K-tiles
// (64 Hh/Wd + 8 Ac/Wcat). LDS 48 KiB -> 3 blocks/CU; VMCNT(4).
// ---------------------------------------------------------------------------
__global__ __launch_bounds__(256,2) void mfma_final(
    const u16* __restrict__ Hh, const u16* __restrict__ Wd_,
    const u16* __restrict__ Ac, const u16* __restrict__ Wcat,
    const float* __restrict__ bd, const float* __restrict__ sumw,
    float* __restrict__ out)
{
    // buf (8192 u16 = 16 KiB): A 128x32 @0, B 128x32 @4096
    __shared__ __align__(16) u16 lds[24576];   // 48 KiB = 3 bufs
    const int t = threadIdx.x, lane = t & 63, wv = t >> 6;
    const int l31 = lane & 31, kh = lane >> 5;
    const int wr = wv & 1, wc = wv >> 1;
    const int m0 = blockIdx.y * 128, n0 = blockIdx.x * 128;

    const int srow = t >> 2;
    const int gcol = (((t & 3) ^ ((t >> 3) & 3)) * 8);
    const u16* gA1 = Hh   + (long)(m0 + srow) * HH  + gcol;
    const u16* gB1 = Wd_  + (long)(n0 + srow) * HH  + gcol;
    const u16* gA2 = Ac   + (long)(m0 + srow) * 256 + gcol;
    const u16* gB2 = Wcat + (long)(n0 + srow) * 256 + gcol;
    const int st8 = t * 8;

    const int sw3 = (l31 >> 1) & 3;
    int offA[2][2], offB[2][2];
    #pragma unroll
    for (int m = 0; m < 2; ++m)
        #pragma unroll
        for (int ks = 0; ks < 2; ++ks) {
            const int ko = ((ks*2 + kh) ^ sw3) * 8;
            offA[m][ks] =        (wr*64 + m*32 + l31)*32 + ko;
            offB[m][ks] = 4096 + (wc*64 + m*32 + l31)*32 + ko;
        }

    f32x16 acc[2][2]  = {};
    f32x16 acc2[2][2] = {};

    auto stage = [&](int tk) {
        u16* Lb = lds + (tk % 3) * 8192;
        if (tk < 64) {
            const int k0 = tk * 32;
            gld16(gA1 + k0,           Lb + st8);
            gld16(gA1 + 64L*HH + k0,  Lb + 2048 + st8);
            gld16(gB1 + k0,           Lb + 4096 + st8);
            gld16(gB1 + 64L*HH + k0,  Lb + 6144 + st8);
        } else {
            const int k0 = (tk - 64) * 32;
            gld16(gA2 + k0,           Lb + st8);
            gld16(gA2 + 64L*256 + k0, Lb + 2048 + st8);
            gld16(gB2 + k0,           Lb + 4096 + st8);
            gld16(gB2 + 64L*256 + k0, Lb + 6144 + st8);
        }
    };

    auto compute = [&](int tk, f32x16 (&A)[2][2]) {
        const u16* Lb = lds + (tk % 3) * 8192;
        bf16x8 a[2][2], b[2][2];
        #pragma unroll
        for (int m = 0; m < 2; ++m)
            #pragma unroll
            for (int ks = 0; ks < 2; ++ks) {
                a[m][ks] = *(const bf16x8*)&Lb[offA[m][ks]];
                b[m][ks] = *(const bf16x8*)&Lb[offB[m][ks]];
            }
        __builtin_amdgcn_s_setprio(1);
        #pragma unroll
        for (int m = 0; m < 2; ++m)
            #pragma unroll
            for (int n = 0; n < 2; ++n)
                #pragma unroll
                for (int ks = 0; ks < 2; ++ks)
                    A[m][n] = __builtin_amdgcn_mfma_f32_32x32x16_bf16(a[m][ks], b[n][ks], A[m][n], 0, 0, 0);
        __builtin_amdgcn_s_setprio(0);
    };

    stage(0); stage(1);
    #pragma unroll 1
    for (int tt = 0; tt < 70; ++tt) {
        VMCNT(4);
        __builtin_amdgcn_s_barrier();
        __builtin_amdgcn_sched_barrier(0);
        stage(tt + 2);
        if (tt < 64) compute(tt, acc); else compute(tt, acc2);
    }
    VMCNT(4);
    __builtin_amdgcn_s_barrier();
    __builtin_amdgcn_sched_barrier(0);
    compute(70, acc2);
    VMCNT(0);
    __builtin_amdgcn_s_barrier();
    __builtin_amdgcn_sched_barrier(0);
    compute(71, acc2);

    #pragma unroll
    for (int n = 0; n < 2; ++n) {
        const int col = n0 + wc*64 + n*32 + l31;
        const float bdc = bd[col];
        #pragma unroll
        for (int m = 0; m < 2; ++m)
            #pragma unroll
            for (int r = 0; r < 16; ++r) {
                const int row = m0 + wr*64 + m*32 + (r & 3) + 8*(r >> 2) + 4*kh;
                out[(long)row * DD + col] =
                    sumw[row] * (acc[m][n][r] + bdc) + 0.1f * acc2[m][n][r];
            }
    }
}

// ---------------------------------------------------------------------------
// Flash with deterministic T-partials. grid = (8 t-groups, 16 s-tiles, 4 b).
// ---------------------------------------------------------------------------
__global__ __launch_bounds__(256,2) void flash_pv(
    const u16* __restrict__ ai, const u16* __restrict__ ao,
    const u16* __restrict__ aiT, float* __restrict__ adaptP)
{
    __shared__ __align__(16) u16 As[128*32];
    __shared__ __align__(16) u16 Bs[128*32];
    __shared__ __align__(16) u16 Psh[128*PS];
    const int t = threadIdx.x, lane = t & 63, wv = t >> 6;
    const int fr = lane & 15, q = lane >> 4;
    const int wm = (wv & 1) * 64, wn = (wv >> 1) * 64;
    const int tg = blockIdx.x, s0 = blockIdx.y * 128, b = blockIdx.z;
    const u16* aib  = ai  + (long)b * SS * AD;
    const u16* aob  = ao  + (long)b * SS * AD;
    const u16* aiTb = aiT + (long)b * AD * SS;
    const int srow = t >> 2, scol = (t & 3) * 8;
    u16* la0 = As + t * 8;  u16* la1 = As + 2048 + t * 8;
    u16* lb0 = Bs + t * 8;  u16* lb1 = Bs + 2048 + t * 8;
    const u16* ga0 = aib + (long)(s0 + srow) * AD + scol;
    const u16* ga1 = ga0 + 64L * AD;

    f32x4 vacc[4][4] = {};
    for (int ti = 0; ti < 2; ++ti) {
        const int t0 = tg * 256 + ti * 128;
        const u16* gb0 = aob + (long)(t0 + srow) * AD + scol;
        const u16* gb1 = gb0 + 64L * AD;
        f32x4 acc[4][4] = {};
        for (int k0 = 0; k0 < AD; k0 += 32) {
            gld16(ga0 + k0, la0);
            gld16(ga1 + k0, la1);
            gld16(gb0 + k0, lb0);
            gld16(gb1 + k0, lb1);
            __syncthreads();
            bf16x8 af[4], bfr[4];
            #pragma unroll
            for (int i = 0; i < 4; ++i) af[i]  = *(const bf16x8*)&As[(wm + i*16 + fr)*32 + q*8];
            #pragma unroll
            for (int i = 0; i < 4; ++i) bfr[i] = *(const bf16x8*)&Bs[(wn + i*16 + fr)*32 + q*8];
            #pragma unroll
            for (int mi = 0; mi < 4; ++mi)
                #pragma unroll
                for (int ni = 0; ni < 4; ++ni)
                    acc[mi][ni] = __builtin_amdgcn_mfma_f32_16x16x32_bf16(af[mi], bfr[ni], acc[mi][ni], 0, 0, 0);
            __syncthreads();
        }
        // P -> Psh (bf16)
        #pragma unroll
        for (int mi = 0; mi < 4; ++mi)
            #pragma unroll
            for (int ni = 0; ni < 4; ++ni)
                #pragma unroll
                for (int r = 0; r < 4; ++r) {
                    float v = acc[mi][ni][r];
                    v = fminf(fmaxf(v, -5.f), 5.f);
                    Psh[(wm + mi*16 + q*4 + r)*PS + wn + ni*16 + fr] = f2bf(silu_f(v));
                }
        __syncthreads();
        // PV: vacc += Psh @ aiT-tile (B frags direct from global, L2-hot)
        #pragma unroll
        for (int kk = 0; kk < 4; ++kk) {
            bf16x8 pf[4], bi[4];
            #pragma unroll
            for (int mi = 0; mi < 4; ++mi)
                pf[mi] = *(const bf16x8*)&Psh[(wm + mi*16 + fr)*PS + kk*32 + q*8];
            #pragma unroll
            for (int ni = 0; ni < 4; ++ni)
                bi[ni] = *(const bf16x8*)&aiTb[(long)(wn + ni*16 + fr)*SS + t0 + kk*32 + q*8];
            #pragma unroll
            for (int mi = 0; mi < 4; ++mi)
                #pragma unroll
                for (int ni = 0; ni < 4; ++ni)
                    vacc[mi][ni] = __builtin_amdgcn_mfma_f32_16x16x32_bf16(pf[mi], bi[ni], vacc[mi][ni], 0, 0, 0);
        }
    }
    float* Pf = adaptP + (long)tg * MM * AD + (long)(b * SS + s0) * AD;
    #pragma unroll
    for (int mi = 0; mi < 4; ++mi)
        #pragma unroll
        for (int ni = 0; ni < 4; ++ni) {
            const int col = wn + ni*16 + fr;
            #pragma unroll
            for (int r = 0; r < 4; ++r) {
                const int row = wm + mi*16 + q*4 + r;
                Pf[(long)row * AD + col] = vacc[mi][ni][r];
            }
        }
}

// Sum 8 T-partials * sumw -> acat[:,128:256] bf16.
__global__ __launch_bounds__(256) void scale_adapt(
    const float* __restrict__ P, const float* __restrict__ sumw, u16* __restrict__ acat)
{
    const int i = blockIdx.x * 256 + threadIdx.x;   // MM*AD/4
    float4 v = ((const float4*)P)[i];
    #pragma unroll
    for (int tg = 1; tg < 8; ++tg) {
        const float4 w = ((const float4*)P)[i + (long)tg * (MM*AD/4)];
        v.x += w.x; v.y += w.y; v.z += w.z; v.w += w.w;
    }
    const long grow = i >> 5;
    const float sw = sumw[grow];
    ushort4 o;
    o.x = f2bf(sw*v.x); o.y = f2bf(sw*v.y); o.z = f2bf(sw*v.z); o.w = f2bf(sw*v.w);
    ((ushort4*)acat)[grow*64 + 32 + (i & 31)] = o;
}

// ---------------------------------------------------------------------------
// Fused expert branch, 32-row blocks (grid MM/32 = 256). 4 waves:
// (wv&1) = row half, (wv>>1) = expert half {0-3 | 4-7}; LDS combine.
// ---------------------------------------------------------------------------
__global__ __launch_bounds__(256) void expert_fused(
    const u16* __restrict__ pre, const u16* __restrict__ aexp,
    const float* __restrict__ ew, const float* __restrict__ eg,
    const float* __restrict__ eb, u16* __restrict__ acat,
    float* __restrict__ sumw)
{
    __shared__ float ewsh[32*8];
    __shared__ float egsh[8*128], ebsh[8*128];
    __shared__ float part[32*132];   // padded stride vs bank conflicts
    const int t = threadIdx.x, lane = t & 63, wv = t >> 6;
    const int fr = lane & 15, q = lane >> 4;
    const int wm = (wv & 1) * 16;
    const int e0 = (wv >> 1) * 4;
    const int m0 = blockIdx.x * 32;
    if (t < 64) {
        const int row = t >> 1, j = (t & 1)*4;
        *(float4*)&ewsh[row*8+j] = *(const float4*)&ew[(long)(m0+row)*EE + j];
    }
    {   const int e = t >> 5, c = (t & 31)*4;
        *(float4*)&egsh[e*128+c] = *(const float4*)&eg[e*128+c];
        *(float4*)&ebsh[e*128+c] = *(const float4*)&eb[e*128+c]; }
    __syncthreads();

    f32x4 hwacc[8] = {};
    for (int ee = 0; ee < 4; ++ee) {
        const int e = e0 + ee;
        f32x4 acc[8] = {};
        const u16* Ae = aexp + (long)e * AD * AD;
        #pragma unroll
        for (int ks = 0; ks < 4; ++ks) {
            bf16x8 af, bfr[8];
            af = *(const bf16x8*)&pre[(long)(m0 + wm + fr)*AD + ks*32 + q*8];
            #pragma unroll
            for (int ni = 0; ni < 8; ++ni)
                bfr[ni] = *(const bf16x8*)&Ae[(long)(ni*16 + fr)*AD + ks*32 + q*8];
            #pragma unroll
            for (int ni = 0; ni < 8; ++ni)
                acc[ni] = __builtin_amdgcn_mfma_f32_16x16x32_bf16(af, bfr[ni], acc[ni], 0, 0, 0);
        }
        #pragma unroll
        for (int r = 0; r < 4; ++r) {
            float s = 0.f, s2 = 0.f;
            #pragma unroll
            for (int ni = 0; ni < 8; ++ni) { const float v = acc[ni][r]; s += v; s2 += v*v; }
            #pragma unroll
            for (int msk = 1; msk < 16; msk <<= 1) {
                s  += __shfl_xor(s,  msk, 64);
                s2 += __shfl_xor(s2, msk, 64);
            }
            const float mean = s * (1.f/128.f);
            const float var  = s2 * (1.f/128.f) - mean*mean;
            const float rs   = rsqrtf(var + 1e-5f);
            const int rowl = wm + q*4 + r;
            float w = ewsh[rowl*8 + e]; w = w > 0.f ? w : 0.f;
            #pragma unroll
            for (int ni = 0; ni < 8; ++ni) {
                const int col = ni*16 + fr;
                hwacc[ni][r] += w * ((acc[ni][r] - mean) * rs * egsh[e*128+col] + ebsh[e*128+col]);
            }
        }
    }
    if (wv >= 2) {
        #pragma unroll
        for (int r = 0; r < 4; ++r) {
            const int rowl = wm + q*4 + r;
            #pragma unroll
            for (int ni = 0; ni < 8; ++ni)
                part[rowl*132 + ni*16 + fr] = hwacc[ni][r];
        }
    }
    __syncthreads();
    if (wv < 2) {
        #pragma unroll
        for (int r = 0; r < 4; ++r) {
            const int rowl = wm + q*4 + r;
            #pragma unroll
            for (int ni = 0; ni < 8; ++ni) {
                const float v = hwacc[ni][r] + part[rowl*132 + ni*16 + fr];
                acat[(long)(m0+rowl)*256 + ni*16 + fr] = f2bf(v);
            }
            if (fr == 0) {
                float sw = 0.f;
                #pragma unroll
                for (int j = 0; j < 8; ++j) sw += ewsh[rowl*8 + j];
                sumw[m0 + rowl] = sw;
            }
        }
    }
}

// ---------------------------------------------------------------------------
// Split-K reduce + bias + (optional raw bf16 out) + LayerNorm(128) -> bf16.
// 256 thr = 2 rows/block (grid MM/2); wave shfl reduce + 1 barrier.
// ---------------------------------------------------------------------------
template<int S>
__global__ __launch_bounds__(256) void ln_reduce(
    const float* __restrict__ P, long sSplit, const float* __restrict__ bias,
    u16* __restrict__ raw, u16* __restrict__ ln_out,
    const float* __restrict__ g, const float* __restrict__ b)
{
    const int half = threadIdx.x >> 7;      // row parity within block
    const int c = threadIdx.x & 127;
    const long r = (long)blockIdx.x * 2 + half;
    float v = bias[c];
    #pragma unroll
    for (int s = 0; s < S; ++s) v += P[(long)s * sSplit + r * AD + c];
    if (raw) raw[r * AD + c] = f2bf(v);
    float s1 = v, s2 = v*v;
    #pragma unroll
    for (int m = 1; m < 64; m <<= 1) {
        s1 += __shfl_xor(s1, m, 64);
        s2 += __shfl_xor(s2, m, 64);
    }
    __shared__ float ws1[4], ws2[4];
    const int wv = threadIdx.x >> 6;        // waves {0,1}=row0, {2,3}=row1
    if ((threadIdx.x & 63) == 0) { ws1[wv] = s1; ws2[wv] = s2; }
    __syncthreads();
    const float S1 = ws1[half*2] + ws1[half*2+1];
    const float S2 = ws2[half*2] + ws2[half*2+1];
    const float mean = S1 * (1.f/AD);
    const float var  = S2 * (1.f/AD) - mean*mean;
    const float rs   = rsqrtf(var + 1e-5f);
    ln_out[r * AD + c] = f2bf((v - mean) * rs * g[c] + b[c]);
}

// Reduce wc partials (S=16, z=2) -> Wcat [1024, 256] bf16.
__global__ __launch_bounds__(256) void reduce_cat(
    const float* __restrict__ P, u16* __restrict__ Wcat)
{
    const int i = blockIdx.x * 256 + threadIdx.x;   // 65536 total
    const int a4 = i & 31, z = (i >> 5) & 1, d = i >> 6;
    const float* src = P + (long)z * (16L*DD*AD) + (long)d * AD + a4*4;
    float4 v = *(const float4*)src;
    #pragma unroll
    for (int s = 1; s < 16; ++s) {
        const float4 w = *(const float4*)(src + (long)s * DD * AD);
        v.x += w.x; v.y += w.y; v.z += w.z; v.w += w.w;
    }
    ushort4 o; o.x=f2bf(v.x); o.y=f2bf(v.y); o.z=f2bf(v.z); o.w=f2bf(v.w);
    ((ushort4*)Wcat)[(long)d*64 + z*32 + a4] = o;
}

// Combined bf16 transpose [2048,128]->[128,2048]: z<2: Wp/Wap; z>=2: ai batch z-2.
__global__ __launch_bounds__(256) void transpose6(
    const u16* __restrict__ wRaw, u16* __restrict__ wT,
    const u16* __restrict__ ai, u16* __restrict__ aiT)
{
    __shared__ u16 tile[32][33];
    const int z = blockIdx.z;
    const u16* in; u16* out;
    if (z < 2) { in = wRaw + (long)z * HH * AD; out = wT + (long)z * AD * HH; }
    else       { in = ai + (long)(z-2) * SS * AD; out = aiT + (long)(z-2) * AD * SS; }
    const int x0 = blockIdx.x * 32, y0 = blockIdx.y * 32;
    const int tx = threadIdx.x & 31, ty = threadIdx.x >> 5;
    #pragma unroll
    for (int j = 0; j < 4; ++j)
        tile[ty + j*8][tx] = in[(long)(y0 + ty + j*8) * AD + x0 + tx];
    __syncthreads();
    #pragma unroll
    for (int j = 0; j < 4; ++j)
        out[(long)(x0 + ty + j*8) * SS + y0 + tx] = tile[tx][ty + j*8];
}

// Packed f32->bf16 convert: 5 segments, 4 elems/thread. cum[] in float4 units.
struct Cvt5 { const float* in[5]; u16* out[5]; long cum[6]; };
__global__ __launch_bounds__(256) void cvt_pack(Cvt5 a)
{
    const long i = (long)blockIdx.x * 256 + threadIdx.x;
    if (i >= a.cum[5]) return;
    int s = 0;
    while (i >= a.cum[s+1]) ++s;
    const long j = i - a.cum[s];
    const float4 v = ((const float4*)a.in[s])[j];
    ushort4 o;
    o.x = f2bf(v.x); o.y = f2bf(v.y); o.z = f2bf(v.z); o.w = f2bf(v.w);
    ((ushort4*)a.out[s])[j] = o;
}

extern "C" void kernel_launch(void* const* d_in, const int* in_sizes, int n_in,
                              void* d_out, int out_size, void* d_ws, size_t ws_size,
                              hipStream_t stream) {
    const float* x    = (const float*)d_in[0];
    const float* ew   = (const float*)d_in[1];
    const float* Wu   = (const float*)d_in[2];
    const float* bu   = (const float*)d_in[3];
    const float* Wg   = (const float*)d_in[4];
    const float* bg   = (const float*)d_in[5];
    const float* Wd   = (const float*)d_in[6];
    const float* bd   = (const float*)d_in[7];
    const float* Wpre = (const float*)d_in[8];
    const float* bpre = (const float*)d_in[9];
    const float* Wpost= (const float*)d_in[10];
    const float* bpost= (const float*)d_in[11];
    const float* ln_g = (const float*)d_in[12];
    const float* ln_b = (const float*)d_in[13];
    const float* Wap  = (const float*)d_in[14];
    const float* Aex  = (const float*)d_in[15];
    const float* eg   = (const float*)d_in[16];
    const float* eb   = (const float*)d_in[17];
    const float* Wp   = (const float*)d_in[18];
    const float* Wo   = (const float*)d_in[19];
    float* out = (float*)d_out;

    // ---- workspace layout ----
    char* p = (char*)d_ws;
    auto take = [&](long bytes) -> char* {
        char* r = p; p += (bytes + 255) & ~255L; return r;
    };
    u16* x_slot  = (u16*)take(16777216);          // x_bf phase1; sub-slots phase2
    u16* wslot   = (u16*)take((long)2*DD*HH*2);   // 8MB: [Wu|Wg] then [Wo|Wd]
    u16* wpre    = (u16*)take((long)AD*DD*2);
    u16* aex     = (u16*)take((long)EE*AD*AD*2);
    u16* pre_bf  = (u16*)take((long)MM*AD*2);
    u16* ai_bf   = (u16*)take((long)MM*AD*2);
    char* shareA = take(33554432);                // preP(16MB)/wcP(16MB@+16)/wpostP(16MB)/adaptP(32MB)
    u16* acat    = (u16*)take((long)MM*256*2);    // [hw | sumw*adapt]
    float* sumw  = (float*)take((long)MM*4);
    u16* hidden  = (u16*)take((long)MM*HH*2);

    // x_slot sub-layout (phase 2):
    u16* x_bf    = x_slot;
    u16* aiT     = x_slot;                         // 4*128*2048 = 1,048,576 u16
    u16* wRaw    = aiT  + 1048576;                 // [Wp|Wap]: 524,288
    u16* wT      = wRaw + 524288;                  // [WpT|WapT]: 524,288
    u16* wpost_w = wT   + 524288;                  // 262,144
    u16* wcat    = wpost_w + 262144;               // 262,144
    u16* ao_bf   = wcat + 262144;                  // 1,048,576
    float* preP   = (float*)shareA;
    float* wcP    = (float*)(shareA + 16777216);   // 16MB (steps 8-9; preP dead)
    float* wpostP = (float*)shareA;
    float* adaptP = (float*)shareA;                // 8 x MM*AD f32 = 32MB

    // 1. converts phase 1: x, Wu, Wg, Wpre, Aex
    {
        Cvt5 a;
        a.in[0]=x;    a.out[0]=x_bf;              long n0=(long)MM*DD/4;
        a.in[1]=Wu;   a.out[1]=wslot;             long n1=(long)HH*DD/4;
        a.in[2]=Wg;   a.out[2]=wslot+(long)DD*HH; long n2=(long)HH*DD/4;
        a.in[3]=Wpre; a.out[3]=wpre;              long n3=(long)AD*DD/4;
        a.in[4]=Aex;  a.out[4]=aex;               long n4=(long)EE*AD*AD/4;
        a.cum[0]=0; a.cum[1]=n0; a.cum[2]=n0+n1; a.cum[3]=n0+n1+n2;
        a.cum[4]=n0+n1+n2+n3; a.cum[5]=n0+n1+n2+n3+n4;
        cvt_pack<<<dim3((a.cum[5]+255)/256), 256, 0, stream>>>(a);
    }
    // 2. pre partials: x @ Wpre^T, split-K S=4
    mfma_sk<<<dim3(4, MM/128, 1), 256, 0, stream>>>(
        x_bf, wpre, preP, MM, DD, 4, 0, 0, 0, (long)MM*AD);
    // 3. reduce + bpre -> pre_bf (raw) and ai_bf (LN)
    ln_reduce<4><<<dim3(MM/2), 256, 0, stream>>>(preP, (long)MM*AD, bpre, pre_bf, ai_bf, ln_g, ln_b);
    // 4. fused expert branch -> acat[:,0:128], sumw  [32-row blocks, grid 256]
    expert_fused<<<dim3(MM/32), 256, 0, stream>>>(pre_bf, aex, ew, eg, eb, acat, sumw);
    // 5. hidden = bf16(silu(x@Wg^T+bg)*(x@Wu^T+bu))  [256x128 depth-3 ring]
    mfma_upgate<<<dim3(HH/128, MM/256), 512, 0, stream>>>(
        x_bf, wslot, wslot+(long)DD*HH, bu, bg, hidden);
    // 6. converts phase 2: Wo, Wd, Wpost, Wp, Wap  (x_bf/Wu/Wg dead)
    {
        Cvt5 a;
        a.in[0]=Wo;    a.out[0]=wslot;             long n0=(long)DD*HH/4;
        a.in[1]=Wd;    a.out[1]=wslot+(long)DD*HH; long n1=(long)DD*HH/4;
        a.in[2]=Wpost; a.out[2]=wpost_w;           long n2=(long)AD*HH/4;
        a.in[3]=Wp;    a.out[3]=wRaw;              long n3=(long)HH*AD/4;
        a.in[4]=Wap;   a.out[4]=wRaw+(long)HH*AD;  long n4=(long)HH*AD/4;
        a.cum[0]=0; a.cum[1]=n0; a.cum[2]=n0+n1; a.cum[3]=n0+n1+n2;
        a.cum[4]=n0+n1+n2+n3; a.cum[5]=n0+n1+n2+n3+n4;
        cvt_pack<<<dim3((a.cum[5]+255)/256), 256, 0, stream>>>(a);
    }
    // 7. transposes: [WpT|WapT] (z=0,1) and aiT per batch (z=2..5)
    transpose6<<<dim3(4,64,6), 256, 0, stream>>>(wRaw, wT, ai_bf, aiT);
    // 8. Wc=Wo@Wp, Wdap=Wd@Wap: split-K S=16 (grid 256)
    mfma_sk<<<dim3(16, DD/128, 2), 256, 0, stream>>>(
        wslot, wT, wcP, DD, HH, 16, (long)DD*HH, (long)AD*HH, 16L*DD*AD, (long)DD*AD);
    // 9. Wcat[d, 0:128]=Wc, [128:256]=Wdap
    reduce_cat<<<dim3(256), 256, 0, stream>>>(wcP, wcat);
    // 10. hidden @ Wpost^T partials, split-K S=4 (was 8; halves partial traffic)
    mfma_sk<<<dim3(4, MM/128, 1), 256, 0, stream>>>(
        hidden, wpost_w, wpostP, MM, HH, 4, 0, 0, 0, (long)MM*AD);
    // 11. ao_bf = LN(. + bpost)
    ln_reduce<4><<<dim3(MM/2), 256, 0, stream>>>(wpostP, (long)MM*AD, bpost, nullptr, ao_bf, ln_g, ln_b);
    // 12. flash: adaptP[tg] = partial_t( silu(clip(ai@ao^T)) @ ai )
    flash_pv<<<dim3(8, SS/128, BB), 256, 0, stream>>>(ai_bf, ao_bf, aiT, adaptP);
    // 13. acat[:,128:256] = bf16(sumw * sum_tg adaptP)
    scale_adapt<<<dim3((long)MM*AD/4/256), 256, 0, stream>>>(adaptP, sumw, acat);
    // 14. out = sumw*(hidden@Wd^T + bd) + 0.1*(acat@Wcat^T)  [128^2 ring, grid 512]
    mfma_final<<<dim3(DD/128, MM/128), 256, 0, stream>>>(
        hidden, wslot+(long)DD*HH, acat, wcat, bd, sumw, out);
}

// Round 9
// 374.198 us; speedup vs baseline: 1.0670x; 1.0464x over previous
//
#include <hip/hip_runtime.h>
#include <math.h>

// Problem constants
#define BB 4
#define SS 2048
#define DD 1024
#define HH 2048
#define AD 128
#define EE 8
#define MM (BB*SS)   // 8192
#define PS 136       // Psh row stride (u16): 272B, 16B-aligned

typedef unsigned short u16;
typedef short bf16x8 __attribute__((ext_vector_type(8)));
typedef float f32x4 __attribute__((ext_vector_type(4)));
typedef float f32x16 __attribute__((ext_vector_type(16)));

__device__ __forceinline__ float silu_f(float x){ return x / (1.f + __expf(-x)); }

__device__ __forceinline__ u16 f2bf(float f){
    union { float f; unsigned u; } c; c.f = f;
    unsigned r = (c.u + 0x7FFFu + ((c.u >> 16) & 1u)) >> 16;
    return (u16)r;
}

__device__ __forceinline__ float bf2f(u16 h){
    union { unsigned u; float f; } c; c.u = ((unsigned)h) << 16;
    return c.f;
}

// async global->LDS, 16B per lane. LDS dest must be wave-uniform base + lane*16.
__device__ __forceinline__ void gld16(const u16* g, u16* l){
    __builtin_amdgcn_global_load_lds((const __attribute__((address_space(1))) void*)g,
                                     (__attribute__((address_space(3))) void*)l, 16, 0, 0);
}

#define VMCNT(n) asm volatile("s_waitcnt vmcnt(" #n ")" ::: "memory")

// ---------------------------------------------------------------------------
// Split-K NT GEMM (16x16x32), N fixed = 128. grid = (S, M/128, Z).
// Depth-4 ring (64 KiB -> 2 blocks/CU), stage-ahead-3, VMCNT(8),
// 1 barrier/K-tile. RING INVARIANT: depth(4) > stage_ahead(3).
// Partials written as bf16 (halves split-K traffic; partial sums are
// <=512-term f32 accumulations, bf16 rel err 0.2% -- absmax headroom 4x).
// Requires Ks/32 >= 4 (call sites: NT = 8, 4, 16).
// ---------------------------------------------------------------------------
__global__ __launch_bounds__(256,2) void mfma_sk(
    const u16* __restrict__ A, const u16* __restrict__ B, u16* __restrict__ P,
    int M, int K, int S, long sA, long sB, long sC, long sSplit)
{
    __shared__ __align__(16) u16 lds[32768];   // 4 bufs x 8192 u16 (As 4096 | Bs 4096)
    const int t = threadIdx.x;
    const int lane = t & 63;
    const int wv = t >> 6;
    const int s = blockIdx.x;
    const int m0 = blockIdx.y * 128;
    const u16* Ab = A + (long)blockIdx.z * sA;
    const u16* Bb = B + (long)blockIdx.z * sB;
    const int srow = t >> 2;
    const int gcol = (((t & 3) ^ ((t >> 3) & 3)) * 8);   // pre-swizzled source col
    const int Ks = K / S, kBeg = s * Ks;
    const int NT = Ks >> 5;
    const u16* ga0 = Ab + (long)(m0 + srow) * K + gcol + kBeg;
    const u16* ga1 = ga0 + 64L * K;
    const u16* gb0 = Bb + (long)srow * K + gcol + kBeg;
    const u16* gb1 = gb0 + 64L * K;
    const int fr = lane & 15, q = lane >> 4;
    const int wm = (wv & 1) * 64, wn = (wv >> 1) * 64;
    const int st8 = t * 8;

    // read-side swizzle: chunk' = chunk ^ ((row>>1)&3); row bases mult of 16
    const int sw3 = (fr >> 1) & 3;
    const int koff = (q ^ sw3) * 8;

    f32x4 acc[4][4] = {};

    auto stage = [&](int tk) {
        u16* Lb = lds + (tk & 3) * 8192;
        const int k0 = tk * 32;
        gld16(ga0 + k0, Lb + st8);
        gld16(ga1 + k0, Lb + 2048 + st8);
        gld16(gb0 + k0, Lb + 4096 + st8);
        gld16(gb1 + k0, Lb + 6144 + st8);
    };
    auto compute = [&](int tk) {
        const u16* Lb = lds + (tk & 3) * 8192;
        bf16x8 af[4], bfr[4];
        #pragma unroll
        for (int i = 0; i < 4; ++i) af[i]  = *(const bf16x8*)&Lb[(wm + i*16 + fr)*32 + koff];
        #pragma unroll
        for (int i = 0; i < 4; ++i) bfr[i] = *(const bf16x8*)&Lb[4096 + (wn + i*16 + fr)*32 + koff];
        __builtin_amdgcn_s_setprio(1);
        #pragma unroll
        for (int mi = 0; mi < 4; ++mi)
            #pragma unroll
            for (int ni = 0; ni < 4; ++ni)
                acc[mi][ni] = __builtin_amdgcn_mfma_f32_16x16x32_bf16(af[mi], bfr[ni], acc[mi][ni], 0, 0, 0);
        __builtin_amdgcn_s_setprio(0);
    };

    stage(0); stage(1); stage(2);
    #pragma unroll 1
    for (int tt = 0; tt < NT - 3; ++tt) {
        VMCNT(8);
        __builtin_amdgcn_s_barrier();
        __builtin_amdgcn_sched_barrier(0);
        stage(tt + 3);
        compute(tt);
    }
    VMCNT(8);
    __builtin_amdgcn_s_barrier();
    __builtin_amdgcn_sched_barrier(0);
    compute(NT - 3);
    VMCNT(4);
    __builtin_amdgcn_s_barrier();
    __builtin_amdgcn_sched_barrier(0);
    compute(NT - 2);
    VMCNT(0);
    __builtin_amdgcn_s_barrier();
    __builtin_amdgcn_sched_barrier(0);
    compute(NT - 1);

    u16* Pf = P + (long)s * sSplit + (long)blockIdx.z * sC;
    #pragma unroll
    for (int mi = 0; mi < 4; ++mi)
        #pragma unroll
        for (int ni = 0; ni < 4; ++ni) {
            const int col = wn + ni*16 + fr;
            #pragma unroll
            for (int r = 0; r < 4; ++r) {
                const int row = m0 + wm + mi*16 + q*4 + r;
                Pf[(long)row * 128 + col] = f2bf(acc[mi][ni][r]);
            }
        }
}

// ---------------------------------------------------------------------------
// Fused up/gate, depth-3 pipelined ring, 256(M)x128(N) tile, BK=32, 512 thr.
// 8 waves = 2M x 4N, per-wave 128x32, both U and G accumulators in-wave.
// 4-deep LDS ring (128 KiB), counted vmcnt(8), 1 barrier per K-tile.
// Measured 83.3-84.7 us (R1/R3/R5/R8). Register-bound at 1 block/CU.
// ---------------------------------------------------------------------------
__global__ __launch_bounds__(512,2) void mfma_upgate(
    const u16* __restrict__ X, const u16* __restrict__ Wu_, const u16* __restrict__ Wg_,
    const float* __restrict__ bu, const float* __restrict__ bg, u16* __restrict__ H)
{
    __shared__ __align__(16) u16 lds[65536];   // 128 KiB
    const int t = threadIdx.x, lane = t & 63, wv = t >> 6;
    const int l31 = lane & 31, kh = lane >> 5;
    const int wr = wv >> 2, wc = wv & 3;          // 2M x 4N wave grid
    const int m0 = blockIdx.y * 256, n0 = blockIdx.x * 128;

    const int srow = t >> 2;
    const int gcol = (((t & 3) ^ ((t >> 3) & 3)) * 8);
    const u16* gx0 = X   + (long)(m0 + srow) * DD + gcol;
    const u16* gx1 = gx0 + 128L * DD;
    const u16* gu  = Wu_ + (long)(n0 + srow) * DD + gcol;
    const u16* gg  = Wg_ + (long)(n0 + srow) * DD + gcol;
    const int st8 = t * 8;

    const int sw3 = (l31 >> 1) & 3;
    int offA[4][2], offB[2];
    #pragma unroll
    for (int m = 0; m < 4; ++m)
        #pragma unroll
        for (int ks = 0; ks < 2; ++ks)
            offA[m][ks] = (wr*128 + m*32 + l31)*32 + (((ks*2 + kh) ^ sw3) * 8);
    #pragma unroll
    for (int ks = 0; ks < 2; ++ks)
        offB[ks] = (wc*32 + l31)*32 + (((ks*2 + kh) ^ sw3) * 8);

    f32x16 accU[4] = {};
    f32x16 accG[4] = {};

    auto stage = [&](int tb) {
        u16* Lb = lds + (tb & 3) * 16384;
        const int k0 = tb * 32;
        gld16(gx0 + k0, Lb + st8);
        gld16(gx1 + k0, Lb + 4096 + st8);
        gld16(gu  + k0, Lb + 8192 + st8);
        gld16(gg  + k0, Lb + 12288 + st8);
    };

    auto compute = [&](int tb) {
        const u16* Lb = lds + (tb & 3) * 16384;
        bf16x8 a[4][2], uf[2], gf[2];
        #pragma unroll
        for (int ks = 0; ks < 2; ++ks) {
            uf[ks] = *(const bf16x8*)&Lb[8192  + offB[ks]];
            gf[ks] = *(const bf16x8*)&Lb[12288 + offB[ks]];
        }
        #pragma unroll
        for (int m = 0; m < 4; ++m)
            #pragma unroll
            for (int ks = 0; ks < 2; ++ks)
                a[m][ks] = *(const bf16x8*)&Lb[offA[m][ks]];
        __builtin_amdgcn_s_setprio(1);
        #pragma unroll
        for (int m = 0; m < 4; ++m)
            #pragma unroll
            for (int ks = 0; ks < 2; ++ks) {
                accU[m] = __builtin_amdgcn_mfma_f32_32x32x16_bf16(a[m][ks], uf[ks], accU[m], 0, 0, 0);
                accG[m] = __builtin_amdgcn_mfma_f32_32x32x16_bf16(a[m][ks], gf[ks], accG[m], 0, 0, 0);
            }
        __builtin_amdgcn_s_setprio(0);
    };

    stage(0); stage(1); stage(2);
    #pragma unroll 1
    for (int tt = 0; tt < 29; ++tt) {
        VMCNT(8);
        __builtin_amdgcn_s_barrier();
        __builtin_amdgcn_sched_barrier(0);
        stage(tt + 3);
        compute(tt);
    }
    VMCNT(8);
    __builtin_amdgcn_s_barrier();
    __builtin_amdgcn_sched_barrier(0);
    compute(29);
    VMCNT(4);
    __builtin_amdgcn_s_barrier();
    __builtin_amdgcn_sched_barrier(0);
    compute(30);
    VMCNT(0);
    __builtin_amdgcn_s_barrier();
    __builtin_amdgcn_sched_barrier(0);
    compute(31);

    const int col = n0 + wc*32 + l31;
    const float bub = bu[col], bgb = bg[col];
    u16* Hp = H + (long)(m0 + wr*128) * HH + col;
    #pragma unroll
    for (int m = 0; m < 4; ++m)
        #pragma unroll
        for (int r = 0; r < 16; ++r) {
            const int rowl = m*32 + (r & 3) + 8*(r >> 2) + 4*kh;
            const float u = accU[m][r] + bub;
            const float g = accG[m][r] + bgb;
            Hp[(long)rowl * HH] = f2bf(silu_f(g) * u);
        }
}

// ---------------------------------------------------------------------------
// Final GEMM, depth-3 ring (stage-ahead-2), 128x128, 256 thr (4 waves 2Mx2N,
// per-wave 64x64). out = sumw*(Hh@Wd^T + bd) + 0.1*(Ac@Wcat^T). 72 K-tiles
// (64 Hh/Wd + 8 Ac/Wcat). LDS 48 KiB -> 3 blocks/CU; VMCNT(4).
// ---------------------------------------------------------------------------
__global__ __launch_bounds__(256,2) void mfma_final(
    const u16* __restrict__ Hh, const u16* __restrict__ Wd_,
    const u16* __restrict__ Ac, const u16* __restrict__ Wcat,
    const float* __restrict__ bd, const float* __restrict__ sumw,
    float* __restrict__ out)
{
    __shared__ __align__(16) u16 lds[24576];   // 48 KiB = 3 bufs
    const int t = threadIdx.x, lane = t & 63, wv = t >> 6;
    const int l31 = lane & 31, kh = lane >> 5;
    const int wr = wv & 1, wc = wv >> 1;
    const int m0 = blockIdx.y * 128, n0 = blockIdx.x * 128;

    const int srow = t >> 2;
    const int gcol = (((t & 3) ^ ((t >> 3) & 3)) * 8);
    const u16* gA1 = Hh   + (long)(m0 + srow) * HH  + gcol;
    const u16* gB1 = Wd_  + (long)(n0 + srow) * HH  + gcol;
    const u16* gA2 = Ac   + (long)(m0 + srow) * 256 + gcol;
    const u16* gB2 = Wcat + (long)(n0 + srow) * 256 + gcol;
    const int st8 = t * 8;

    const int sw3 = (l31 >> 1) & 3;
    int offA[2][2], offB[2][2];
    #pragma unroll
    for (int m = 0; m < 2; ++m)
        #pragma unroll
        for (int ks = 0; ks < 2; ++ks) {
            const int ko = ((ks*2 + kh) ^ sw3) * 8;
            offA[m][ks] =        (wr*64 + m*32 + l31)*32 + ko;
            offB[m][ks] = 4096 + (wc*64 + m*32 + l31)*32 + ko;
        }

    f32x16 acc[2][2]  = {};
    f32x16 acc2[2][2] = {};

    auto stage = [&](int tk) {
        u16* Lb = lds + (tk % 3) * 8192;
        if (tk < 64) {
            const int k0 = tk * 32;
            gld16(gA1 + k0,           Lb + st8);
            gld16(gA1 + 64L*HH + k0,  Lb + 2048 + st8);
            gld16(gB1 + k0,           Lb + 4096 + st8);
            gld16(gB1 + 64L*HH + k0,  Lb + 6144 + st8);
        } else {
            const int k0 = (tk - 64) * 32;
            gld16(gA2 + k0,           Lb + st8);
            gld16(gA2 + 64L*256 + k0, Lb + 2048 + st8);
            gld16(gB2 + k0,           Lb + 4096 + st8);
            gld16(gB2 + 64L*256 + k0, Lb + 6144 + st8);
        }
    };

    auto compute = [&](int tk, f32x16 (&A)[2][2]) {
        const u16* Lb = lds + (tk % 3) * 8192;
        bf16x8 a[2][2], b[2][2];
        #pragma unroll
        for (int m = 0; m < 2; ++m)
            #pragma unroll
            for (int ks = 0; ks < 2; ++ks) {
                a[m][ks] = *(const bf16x8*)&Lb[offA[m][ks]];
                b[m][ks] = *(const bf16x8*)&Lb[offB[m][ks]];
            }
        __builtin_amdgcn_s_setprio(1);
        #pragma unroll
        for (int m = 0; m < 2; ++m)
            #pragma unroll
            for (int n = 0; n < 2; ++n)
                #pragma unroll
                for (int ks = 0; ks < 2; ++ks)
                    A[m][n] = __builtin_amdgcn_mfma_f32_32x32x16_bf16(a[m][ks], b[n][ks], A[m][n], 0, 0, 0);
        __builtin_amdgcn_s_setprio(0);
    };

    stage(0); stage(1);
    #pragma unroll 1
    for (int tt = 0; tt < 70; ++tt) {
        VMCNT(4);
        __builtin_amdgcn_s_barrier();
        __builtin_amdgcn_sched_barrier(0);
        stage(tt + 2);
        if (tt < 64) compute(tt, acc); else compute(tt, acc2);
    }
    VMCNT(4);
    __builtin_amdgcn_s_barrier();
    __builtin_amdgcn_sched_barrier(0);
    compute(70, acc2);
    VMCNT(0);
    __builtin_amdgcn_s_barrier();
    __builtin_amdgcn_sched_barrier(0);
    compute(71, acc2);

    #pragma unroll
    for (int n = 0; n < 2; ++n) {
        const int col = n0 + wc*64 + n*32 + l31;
        const float bdc = bd[col];
        #pragma unroll
        for (int m = 0; m < 2; ++m)
            #pragma unroll
            for (int r = 0; r < 16; ++r) {
                const int row = m0 + wr*64 + m*32 + (r & 3) + 8*(r >> 2) + 4*kh;
                out[(long)row * DD + col] =
                    sumw[row] * (acc[m][n][r] + bdc) + 0.1f * acc2[m][n][r];
            }
    }
}

// ---------------------------------------------------------------------------
// Flash with deterministic T-partials. grid = (8 t-groups, 16 s-tiles, 4 b).
// ---------------------------------------------------------------------------
__global__ __launch_bounds__(256,2) void flash_pv(
    const u16* __restrict__ ai, const u16* __restrict__ ao,
    const u16* __restrict__ aiT, float* __restrict__ adaptP)
{
    __shared__ __align__(16) u16 As[128*32];
    __shared__ __align__(16) u16 Bs[128*32];
    __shared__ __align__(16) u16 Psh[128*PS];
    const int t = threadIdx.x, lane = t & 63, wv = t >> 6;
    const int fr = lane & 15, q = lane >> 4;
    const int wm = (wv & 1) * 64, wn = (wv >> 1) * 64;
    const int tg = blockIdx.x, s0 = blockIdx.y * 128, b = blockIdx.z;
    const u16* aib  = ai  + (long)b * SS * AD;
    const u16* aob  = ao  + (long)b * SS * AD;
    const u16* aiTb = aiT + (long)b * AD * SS;
    const int srow = t >> 2, scol = (t & 3) * 8;
    u16* la0 = As + t * 8;  u16* la1 = As + 2048 + t * 8;
    u16* lb0 = Bs + t * 8;  u16* lb1 = Bs + 2048 + t * 8;
    const u16* ga0 = aib + (long)(s0 + srow) * AD + scol;
    const u16* ga1 = ga0 + 64L * AD;

    f32x4 vacc[4][4] = {};
    for (int ti = 0; ti < 2; ++ti) {
        const int t0 = tg * 256 + ti * 128;
        const u16* gb0 = aob + (long)(t0 + srow) * AD + scol;
        const u16* gb1 = gb0 + 64L * AD;
        f32x4 acc[4][4] = {};
        for (int k0 = 0; k0 < AD; k0 += 32) {
            gld16(ga0 + k0, la0);
            gld16(ga1 + k0, la1);
            gld16(gb0 + k0, lb0);
            gld16(gb1 + k0, lb1);
            __syncthreads();
            bf16x8 af[4], bfr[4];
            #pragma unroll
            for (int i = 0; i < 4; ++i) af[i]  = *(const bf16x8*)&As[(wm + i*16 + fr)*32 + q*8];
            #pragma unroll
            for (int i = 0; i < 4; ++i) bfr[i] = *(const bf16x8*)&Bs[(wn + i*16 + fr)*32 + q*8];
            #pragma unroll
            for (int mi = 0; mi < 4; ++mi)
                #pragma unroll
                for (int ni = 0; ni < 4; ++ni)
                    acc[mi][ni] = __builtin_amdgcn_mfma_f32_16x16x32_bf16(af[mi], bfr[ni], acc[mi][ni], 0, 0, 0);
            __syncthreads();
        }
        // P -> Psh (bf16)
        #pragma unroll
        for (int mi = 0; mi < 4; ++mi)
            #pragma unroll
            for (int ni = 0; ni < 4; ++ni)
                #pragma unroll
                for (int r = 0; r < 4; ++r) {
                    float v = acc[mi][ni][r];
                    v = fminf(fmaxf(v, -5.f), 5.f);
                    Psh[(wm + mi*16 + q*4 + r)*PS + wn + ni*16 + fr] = f2bf(silu_f(v));
                }
        __syncthreads();
        // PV: vacc += Psh @ aiT-tile (B frags direct from global, L2-hot)
        #pragma unroll
        for (int kk = 0; kk < 4; ++kk) {
            bf16x8 pf[4], bi[4];
            #pragma unroll
            for (int mi = 0; mi < 4; ++mi)
                pf[mi] = *(const bf16x8*)&Psh[(wm + mi*16 + fr)*PS + kk*32 + q*8];
            #pragma unroll
            for (int ni = 0; ni < 4; ++ni)
                bi[ni] = *(const bf16x8*)&aiTb[(long)(wn + ni*16 + fr)*SS + t0 + kk*32 + q*8];
            #pragma unroll
            for (int mi = 0; mi < 4; ++mi)
                #pragma unroll
                for (int ni = 0; ni < 4; ++ni)
                    vacc[mi][ni] = __builtin_amdgcn_mfma_f32_16x16x32_bf16(pf[mi], bi[ni], vacc[mi][ni], 0, 0, 0);
        }
    }
    float* Pf = adaptP + (long)tg * MM * AD + (long)(b * SS + s0) * AD;
    #pragma unroll
    for (int mi = 0; mi < 4; ++mi)
        #pragma unroll
        for (int ni = 0; ni < 4; ++ni) {
            const int col = wn + ni*16 + fr;
            #pragma unroll
            for (int r = 0; r < 4; ++r) {
                const int row = wm + mi*16 + q*4 + r;
                Pf[(long)row * AD + col] = vacc[mi][ni][r];
            }
        }
}

// ---------------------------------------------------------------------------
// Merged: (blocks < NB_AD) sum 8 T-partials * sumw -> acat[:,128:256] bf16;
// (blocks >= NB_AD) reduce 16 bf16 wc partials -> Wcat [1024,256] bf16.
// ---------------------------------------------------------------------------
#define NB_AD (MM*AD/4/256)   // 1024
__global__ __launch_bounds__(256) void scale_adapt(
    const float* __restrict__ P, const float* __restrict__ sumw, u16* __restrict__ acat,
    const u16* __restrict__ wcP, u16* __restrict__ Wcat)
{
    if (blockIdx.x < NB_AD) {
        const int i = blockIdx.x * 256 + threadIdx.x;   // MM*AD/4
        float4 v = ((const float4*)P)[i];
        #pragma unroll
        for (int tg = 1; tg < 8; ++tg) {
            const float4 w = ((const float4*)P)[i + (long)tg * (MM*AD/4)];
            v.x += w.x; v.y += w.y; v.z += w.z; v.w += w.w;
        }
        const long grow = i >> 5;
        const float sw = sumw[grow];
        ushort4 o;
        o.x = f2bf(sw*v.x); o.y = f2bf(sw*v.y); o.z = f2bf(sw*v.z); o.w = f2bf(sw*v.w);
        ((ushort4*)acat)[grow*64 + 32 + (i & 31)] = o;
    } else {
        const int i = (blockIdx.x - NB_AD) * 256 + threadIdx.x;   // 65536 total
        const int a4 = i & 31, z = (i >> 5) & 1, d = i >> 6;
        const u16* src = wcP + (long)z * (16L*DD*AD) + (long)d * AD + a4*4;
        float v0 = 0.f, v1 = 0.f, v2 = 0.f, v3 = 0.f;
        #pragma unroll
        for (int s = 0; s < 16; ++s) {
            const ushort4 w = *(const ushort4*)(src + (long)s * DD * AD);
            v0 += bf2f(w.x); v1 += bf2f(w.y); v2 += bf2f(w.z); v3 += bf2f(w.w);
        }
        ushort4 o; o.x=f2bf(v0); o.y=f2bf(v1); o.z=f2bf(v2); o.w=f2bf(v3);
        ((ushort4*)Wcat)[(long)d*64 + z*32 + a4] = o;
    }
}

// ---------------------------------------------------------------------------
// Fused expert branch, 32-row blocks (grid MM/32 = 256). 4 waves:
// (wv&1) = row half, (wv>>1) = expert half {0-3 | 4-7}; LDS combine.
// ---------------------------------------------------------------------------
__global__ __launch_bounds__(256) void expert_fused(
    const u16* __restrict__ pre, const u16* __restrict__ aexp,
    const float* __restrict__ ew, const float* __restrict__ eg,
    const float* __restrict__ eb, u16* __restrict__ acat,
    float* __restrict__ sumw)
{
    __shared__ float ewsh[32*8];
    __shared__ float egsh[8*128], ebsh[8*128];
    __shared__ float part[32*132];   // padded stride vs bank conflicts
    const int t = threadIdx.x, lane = t & 63, wv = t >> 6;
    const int fr = lane & 15, q = lane >> 4;
    const int wm = (wv & 1) * 16;
    const int e0 = (wv >> 1) * 4;
    const int m0 = blockIdx.x * 32;
    if (t < 64) {
        const int row = t >> 1, j = (t & 1)*4;
        *(float4*)&ewsh[row*8+j] = *(const float4*)&ew[(long)(m0+row)*EE + j];
    }
    {   const int e = t >> 5, c = (t & 31)*4;
        *(float4*)&egsh[e*128+c] = *(const float4*)&eg[e*128+c];
        *(float4*)&ebsh[e*128+c] = *(const float4*)&eb[e*128+c]; }
    __syncthreads();

    f32x4 hwacc[8] = {};
    for (int ee = 0; ee < 4; ++ee) {
        const int e = e0 + ee;
        f32x4 acc[8] = {};
        const u16* Ae = aexp + (long)e * AD * AD;
        #pragma unroll
        for (int ks = 0; ks < 4; ++ks) {
            bf16x8 af, bfr[8];
            af = *(const bf16x8*)&pre[(long)(m0 + wm + fr)*AD + ks*32 + q*8];
            #pragma unroll
            for (int ni = 0; ni < 8; ++ni)
                bfr[ni] = *(const bf16x8*)&Ae[(long)(ni*16 + fr)*AD + ks*32 + q*8];
            #pragma unroll
            for (int ni = 0; ni < 8; ++ni)
                acc[ni] = __builtin_amdgcn_mfma_f32_16x16x32_bf16(af, bfr[ni], acc[ni], 0, 0, 0);
        }
        #pragma unroll
        for (int r = 0; r < 4; ++r) {
            float s = 0.f, s2 = 0.f;
            #pragma unroll
            for (int ni = 0; ni < 8; ++ni) { const float v = acc[ni][r]; s += v; s2 += v*v; }
            #pragma unroll
            for (int msk = 1; msk < 16; msk <<= 1) {
                s  += __shfl_xor(s,  msk, 64);
                s2 += __shfl_xor(s2, msk, 64);
            }
            const float mean = s * (1.f/128.f);
            const float var  = s2 * (1.f/128.f) - mean*mean;
            const float rs   = rsqrtf(var + 1e-5f);
            const int rowl = wm + q*4 + r;
            float w = ewsh[rowl*8 + e]; w = w > 0.f ? w : 0.f;
            #pragma unroll
            for (int ni = 0; ni < 8; ++ni) {
                const int col = ni*16 + fr;
                hwacc[ni][r] += w * ((acc[ni][r] - mean) * rs * egsh[e*128+col] + ebsh[e*128+col]);
            }
        }
    }
    if (wv >= 2) {
        #pragma unroll
        for (int r = 0; r < 4; ++r) {
            const int rowl = wm + q*4 + r;
            #pragma unroll
            for (int ni = 0; ni < 8; ++ni)
                part[rowl*132 + ni*16 + fr] = hwacc[ni][r];
        }
    }
    __syncthreads();
    if (wv < 2) {
        #pragma unroll
        for (int r = 0; r < 4; ++r) {
            const int rowl = wm + q*4 + r;
            #pragma unroll
            for (int ni = 0; ni < 8; ++ni) {
                const float v = hwacc[ni][r] + part[rowl*132 + ni*16 + fr];
                acat[(long)(m0+rowl)*256 + ni*16 + fr] = f2bf(v);
            }
            if (fr == 0) {
                float sw = 0.f;
                #pragma unroll
                for (int j = 0; j < 8; ++j) sw += ewsh[rowl*8 + j];
                sumw[m0 + rowl] = sw;
            }
        }
    }
}

// ---------------------------------------------------------------------------
// Split-K reduce (bf16 partials) + bias + (optional raw bf16 out) +
// LayerNorm(128) -> bf16. 256 thr = 2 rows/block (grid MM/2).
// ---------------------------------------------------------------------------
template<int S>
__global__ __launch_bounds__(256) void ln_reduce(
    const u16* __restrict__ P, long sSplit, const float* __restrict__ bias,
    u16* __restrict__ raw, u16* __restrict__ ln_out,
    const float* __restrict__ g, const float* __restrict__ b)
{
    const int half = threadIdx.x >> 7;      // row parity within block
    const int c = threadIdx.x & 127;
    const long r = (long)blockIdx.x * 2 + half;
    float v = bias[c];
    #pragma unroll
    for (int s = 0; s < S; ++s) v += bf2f(P[(long)s * sSplit + r * AD + c]);
    if (raw) raw[r * AD + c] = f2bf(v);
    float s1 = v, s2 = v*v;
    #pragma unroll
    for (int m = 1; m < 64; m <<= 1) {
        s1 += __shfl_xor(s1, m, 64);
        s2 += __shfl_xor(s2, m, 64);
    }
    __shared__ float ws1[4], ws2[4];
    const int wv = threadIdx.x >> 6;        // waves {0,1}=row0, {2,3}=row1
    if ((threadIdx.x & 63) == 0) { ws1[wv] = s1; ws2[wv] = s2; }
    __syncthreads();
    const float S1 = ws1[half*2] + ws1[half*2+1];
    const float S2 = ws2[half*2] + ws2[half*2+1];
    const float mean = S1 * (1.f/AD);
    const float var  = S2 * (1.f/AD) - mean*mean;
    const float rs   = rsqrtf(var + 1e-5f);
    ln_out[r * AD + c] = f2bf((v - mean) * rs * g[c] + b[c]);
}

// Combined bf16 transpose [2048,128]->[128,2048]: z<2: Wp/Wap; z>=2: ai batch z-2.
__global__ __launch_bounds__(256) void transpose6(
    const u16* __restrict__ wRaw, u16* __restrict__ wT,
    const u16* __restrict__ ai, u16* __restrict__ aiT)
{
    __shared__ u16 tile[32][33];
    const int z = blockIdx.z;
    const u16* in; u16* out;
    if (z < 2) { in = wRaw + (long)z * HH * AD; out = wT + (long)z * AD * HH; }
    else       { in = ai + (long)(z-2) * SS * AD; out = aiT + (long)(z-2) * AD * SS; }
    const int x0 = blockIdx.x * 32, y0 = blockIdx.y * 32;
    const int tx = threadIdx.x & 31, ty = threadIdx.x >> 5;
    #pragma unroll
    for (int j = 0; j < 4; ++j)
        tile[ty + j*8][tx] = in[(long)(y0 + ty + j*8) * AD + x0 + tx];
    __syncthreads();
    #pragma unroll
    for (int j = 0; j < 4; ++j)
        out[(long)(x0 + ty + j*8) * SS + y0 + tx] = tile[tx][ty + j*8];
}

// Packed f32->bf16 convert: 5 segments, 4 elems/thread. cum[] in float4 units.
struct Cvt5 { const float* in[5]; u16* out[5]; long cum[6]; };
__global__ __launch_bounds__(256) void cvt_pack(Cvt5 a)
{
    const long i = (long)blockIdx.x * 256 + threadIdx.x;
    if (i >= a.cum[5]) return;
    int s = 0;
    while (i >= a.cum[s+1]) ++s;
    const long j = i - a.cum[s];
    const float4 v = ((const float4*)a.in[s])[j];
    ushort4 o;
    o.x = f2bf(v.x); o.y = f2bf(v.y); o.z = f2bf(v.z); o.w = f2bf(v.w);
    ((ushort4*)a.out[s])[j] = o;
}

extern "C" void kernel_launch(void* const* d_in, const int* in_sizes, int n_in,
                              void* d_out, int out_size, void* d_ws, size_t ws_size,
                              hipStream_t stream) {
    const float* x    = (const float*)d_in[0];
    const float* ew   = (const float*)d_in[1];
    const float* Wu   = (const float*)d_in[2];
    const float* bu   = (const float*)d_in[3];
    const float* Wg   = (const float*)d_in[4];
    const float* bg   = (const float*)d_in[5];
    const float* Wd   = (const float*)d_in[6];
    const float* bd   = (const float*)d_in[7];
    const float* Wpre = (const float*)d_in[8];
    const float* bpre = (const float*)d_in[9];
    const float* Wpost= (const float*)d_in[10];
    const float* bpost= (const float*)d_in[11];
    const float* ln_g = (const float*)d_in[12];
    const float* ln_b = (const float*)d_in[13];
    const float* Wap  = (const float*)d_in[14];
    const float* Aex  = (const float*)d_in[15];
    const float* eg   = (const float*)d_in[16];
    const float* eb   = (const float*)d_in[17];
    const float* Wp   = (const float*)d_in[18];
    const float* Wo   = (const float*)d_in[19];
    float* out = (float*)d_out;

    // ---- workspace layout ----
    char* p = (char*)d_ws;
    auto take = [&](long bytes) -> char* {
        char* r = p; p += (bytes + 255) & ~255L; return r;
    };
    u16* x_slot  = (u16*)take(16777216);          // x_bf phase1; sub-slots phase2
    u16* wslot   = (u16*)take((long)2*DD*HH*2);   // 8MB: [Wu|Wg] then [Wo|Wd]
    u16* wpre    = (u16*)take((long)AD*DD*2);
    u16* aex     = (u16*)take((long)EE*AD*AD*2);
    u16* pre_bf  = (u16*)take((long)MM*AD*2);
    u16* ai_bf   = (u16*)take((long)MM*AD*2);
    char* shareA = take(33554432);                // preP(8MB)/wpostP(8MB)/adaptP(32MB)
    u16* acat    = (u16*)take((long)MM*256*2);    // [hw | sumw*adapt]
    float* sumw  = (float*)take((long)MM*4);
    u16* hidden  = (u16*)take((long)MM*HH*2);

    // x_slot sub-layout (phase 2):
    u16* x_bf    = x_slot;
    u16* aiT     = x_slot;                         // 4*128*2048 = 1,048,576 u16
    u16* wRaw    = aiT  + 1048576;                 // [Wp|Wap]: 524,288
    u16* wT      = wRaw + 524288;                  // [WpT|WapT]: 524,288
    u16* wpost_w = wT   + 524288;                  // 262,144
    u16* wcat    = wpost_w + 262144;               // 262,144
    u16* ao_bf   = wcat + 262144;                  // 1,048,576
    u16* wcP     = ao_bf + 1048576;                // bf16 wc partials: 16*DD*AD*2z = 4M u16 (8MB)
    u16* preP    = (u16*)shareA;                   // bf16 partials, 4 x MM*AD = 4M u16
    u16* wpostP  = (u16*)shareA;                   // bf16 partials, 4 x MM*AD
    float* adaptP = (float*)shareA;                // 8 x MM*AD f32 = 32MB

    // 1. converts phase 1: x, Wu, Wg, Wpre, Aex
    {
        Cvt5 a;
        a.in[0]=x;    a.out[0]=x_bf;              long n0=(long)MM*DD/4;
        a.in[1]=Wu;   a.out[1]=wslot;             long n1=(long)HH*DD/4;
        a.in[2]=Wg;   a.out[2]=wslot+(long)DD*HH; long n2=(long)HH*DD/4;
        a.in[3]=Wpre; a.out[3]=wpre;              long n3=(long)AD*DD/4;
        a.in[4]=Aex;  a.out[4]=aex;               long n4=(long)EE*AD*AD/4;
        a.cum[0]=0; a.cum[1]=n0; a.cum[2]=n0+n1; a.cum[3]=n0+n1+n2;
        a.cum[4]=n0+n1+n2+n3; a.cum[5]=n0+n1+n2+n3+n4;
        cvt_pack<<<dim3((a.cum[5]+255)/256), 256, 0, stream>>>(a);
    }
    // 2. pre partials (bf16): x @ Wpre^T, split-K S=4
    mfma_sk<<<dim3(4, MM/128, 1), 256, 0, stream>>>(
        x_bf, wpre, preP, MM, DD, 4, 0, 0, 0, (long)MM*AD);
    // 3. reduce + bpre -> pre_bf (raw) and ai_bf (LN)
    ln_reduce<4><<<dim3(MM/2), 256, 0, stream>>>(preP, (long)MM*AD, bpre, pre_bf, ai_bf, ln_g, ln_b);
    // 4. fused expert branch -> acat[:,0:128], sumw  [32-row blocks, grid 256]
    expert_fused<<<dim3(MM/32), 256, 0, stream>>>(pre_bf, aex, ew, eg, eb, acat, sumw);
    // 5. hidden = bf16(silu(x@Wg^T+bg)*(x@Wu^T+bu))  [256x128 depth-3 ring]
    mfma_upgate<<<dim3(HH/128, MM/256), 512, 0, stream>>>(
        x_bf, wslot, wslot+(long)DD*HH, bu, bg, hidden);
    // 6. converts phase 2: Wo, Wd, Wpost, Wp, Wap  (x_bf/Wu/Wg dead)
    {
        Cvt5 a;
        a.in[0]=Wo;    a.out[0]=wslot;             long n0=(long)DD*HH/4;
        a.in[1]=Wd;    a.out[1]=wslot+(long)DD*HH; long n1=(long)DD*HH/4;
        a.in[2]=Wpost; a.out[2]=wpost_w;           long n2=(long)AD*HH/4;
        a.in[3]=Wp;    a.out[3]=wRaw;              long n3=(long)HH*AD/4;
        a.in[4]=Wap;   a.out[4]=wRaw+(long)HH*AD;  long n4=(long)HH*AD/4;
        a.cum[0]=0; a.cum[1]=n0; a.cum[2]=n0+n1; a.cum[3]=n0+n1+n2;
        a.cum[4]=n0+n1+n2+n3; a.cum[5]=n0+n1+n2+n3+n4;
        cvt_pack<<<dim3((a.cum[5]+255)/256), 256, 0, stream>>>(a);
    }
    // 7. transposes: [WpT|WapT] (z=0,1) and aiT per batch (z=2..5)
    transpose6<<<dim3(4,64,6), 256, 0, stream>>>(wRaw, wT, ai_bf, aiT);
    // 8. Wc=Wo@Wp, Wdap=Wd@Wap: split-K S=16 (grid 256), bf16 partials
    mfma_sk<<<dim3(16, DD/128, 2), 256, 0, stream>>>(
        wslot, wT, wcP, DD, HH, 16, (long)DD*HH, (long)AD*HH, 16L*DD*AD, (long)DD*AD);
    // 9. (wc reduce merged into step 13's scale_adapt)
    // 10. hidden @ Wpost^T partials (bf16), split-K S=4
    mfma_sk<<<dim3(4, MM/128, 1), 256, 0, stream>>>(
        hidden, wpost_w, wpostP, MM, HH, 4, 0, 0, 0, (long)MM*AD);
    // 11. ao_bf = LN(. + bpost)
    ln_reduce<4><<<dim3(MM/2), 256, 0, stream>>>(wpostP, (long)MM*AD, bpost, nullptr, ao_bf, ln_g, ln_b);
    // 12. flash: adaptP[tg] = partial_t( silu(clip(ai@ao^T)) @ ai )
    flash_pv<<<dim3(8, SS/128, BB), 256, 0, stream>>>(ai_bf, ao_bf, aiT, adaptP);
    // 13. acat[:,128:256] = bf16(sumw * sum_tg adaptP)  +  Wcat = sum_s wcP
    scale_adapt<<<dim3(NB_AD + 256), 256, 0, stream>>>(adaptP, sumw, acat, wcP, wcat);
    // 14. out = sumw*(hidden@Wd^T + bd) + 0.1*(acat@Wcat^T)  [128^2 ring, grid 512]
    mfma_final<<<dim3(DD/128, MM/128), 256, 0, stream>>>(
        hidden, wslot+(long)DD*HH, acat, wcat, bd, sumw, out);
}